// Round 6
// baseline (2187.972 us; speedup 1.0000x reference)
//
#include <hip/hip_runtime.h>

// ---------- types & helpers ----------
typedef short short8 __attribute__((ext_vector_type(8)));
typedef _Float16 h8 __attribute__((ext_vector_type(8)));
typedef float f32x4 __attribute__((ext_vector_type(4)));

#define DEVI __device__ __forceinline__

DEVI float h2f(short s) { return (float)__builtin_bit_cast(_Float16, s); }
DEVI short f2h(float f) { return __builtin_bit_cast(short, (_Float16)f); }
DEVI f32x4 mfma16(short8 a, short8 b, f32x4 c) {
  return __builtin_amdgcn_mfma_f32_16x16x32_f16(
      __builtin_bit_cast(h8, a), __builtin_bit_cast(h8, b), c, 0, 0, 0);
}

// ---------- DPP payload reductions: (value, index), result in lane 63 ----------
// gfx9 pattern row_shr 1/2/4/8 + row_bcast15/31; identity fills via `old` arg.
DEVI void wave_argmax_pay(float& v, unsigned& i) {
#define STEPP(ctrl)                                                                   \
  {                                                                                   \
    float v2 = __builtin_bit_cast(float, __builtin_amdgcn_update_dpp(                 \
        (int)0xff800000, __builtin_bit_cast(int, v), ctrl, 0xf, 0xf, false));         \
    unsigned i2 = (unsigned)__builtin_amdgcn_update_dpp(                              \
        (int)0xffffffff, (int)i, ctrl, 0xf, 0xf, false);                              \
    bool t = (v2 > v) || (v2 == v && i2 < i);                                         \
    v = t ? v2 : v; i = t ? i2 : i;                                                   \
  }
  STEPP(0x111) STEPP(0x112) STEPP(0x114) STEPP(0x118) STEPP(0x142) STEPP(0x143)
#undef STEPP
}
DEVI void wave_argmin_pay(float& v, unsigned& i) {
#define STEPQ(ctrl)                                                                   \
  {                                                                                   \
    float v2 = __builtin_bit_cast(float, __builtin_amdgcn_update_dpp(                 \
        (int)0x7f800000, __builtin_bit_cast(int, v), ctrl, 0xf, 0xf, false));         \
    unsigned i2 = (unsigned)__builtin_amdgcn_update_dpp(                              \
        (int)0xffffffff, (int)i, ctrl, 0xf, 0xf, false);                              \
    bool t = (v2 < v) || (v2 == v && i2 < i);                                         \
    v = t ? v2 : v; i = t ? i2 : i;                                                   \
  }
  STEPQ(0x111) STEPQ(0x112) STEPQ(0x114) STEPQ(0x118) STEPQ(0x142) STEPQ(0x143)
#undef STEPQ
}

// ---------- weight prep: f16 casts + folded W'' = [w1a | w1b - w1a] ----------
__global__ __launch_bounds__(256) void prep_kernel(
    const float* __restrict__ w2, const float* __restrict__ s1w2,
    const float* __restrict__ s2w2, const float* __restrict__ s1w1,
    const float* __restrict__ s2w1, short* __restrict__ w2b,
    short* __restrict__ s1w2b, short* __restrict__ s2w2b,
    short* __restrict__ W1pp, short* __restrict__ W2pp) {
  int i = blockIdx.x * 256 + threadIdx.x;
  if (i < 4096) {
    w2b[i] = f2h(w2[i]);
  } else if (i < 20480) {
    int j = i - 4096; s1w2b[j] = f2h(s1w2[j]);
  } else if (i < 86016) {
    int j = i - 20480; s2w2b[j] = f2h(s2w2[j]);
  } else if (i < 102400) {
    int j = i - 86016; int c = j & 127;
    float v = s1w1[j]; if (c >= 64) v -= s1w1[j - 64];
    W1pp[j] = f2h(v);
  } else if (i < 167936) {
    int j = i - 102400; int c = j & 255;
    float v = s2w1[j]; if (c >= 128) v -= s2w1[j - 128];
    W2pp[j] = f2h(v);
  }
}

// ---------- stage A: xyz transpose + h0 = x @ w1^T (K=3, VALU fp32) ----------
__global__ __launch_bounds__(256) void stageA_kernel(
    const float* __restrict__ x, const float* __restrict__ w1,
    float* __restrict__ xyz, short* __restrict__ h0) {
  int i = blockIdx.x * 256 + threadIdx.x;  // b*4096 + n, < 131072
  int b = i >> 12, n = i & 4095;
  const float* xb = x + ((size_t)b * 3 << 12) + n;
  float x0 = xb[0], x1 = xb[4096], x2 = xb[8192];
  float* xp = xyz + (size_t)i * 3;
  xp[0] = x0; xp[1] = x1; xp[2] = x2;
  short* hp = h0 + ((size_t)i << 6);
#pragma unroll
  for (int o8 = 0; o8 < 8; ++o8) {
    short8 t;
#pragma unroll
    for (int j = 0; j < 8; ++j) {
      int o = o8 * 8 + j;
      float h = x0 * w1[o * 3] + x1 * w1[o * 3 + 1] + x2 * w1[o * 3 + 2];
      t[j] = f2h(h);
    }
    *reinterpret_cast<short8*>(hp + o8 * 8) = t;
  }
}

// ---------- channel stats for a [M][64] f16 tensor -> transposed partials ----------
__global__ __launch_bounds__(256) void stats64_kernel(
    const short* __restrict__ h, float* __restrict__ partials, int M) {
  __shared__ float l0[256], l1[256];
  const int tid = threadIdx.x;
  const int c = tid & 63, g = tid >> 6;
  float s0 = 0.f, s1 = 0.f;
  for (int m = blockIdx.x * 4 + g; m < M; m += gridDim.x * 4) {
    float v = h2f(h[(size_t)m * 64 + c]);
    s0 += v; s1 += v * v;
  }
  l0[tid] = s0; l1[tid] = s1;
  __syncthreads();
  if (g == 0) {
    for (int w = 1; w < 4; ++w) { s0 += l0[c + w * 64]; s1 += l1[c + w * 64]; }
    partials[(size_t)c * gridDim.x + blockIdx.x] = s0;
    partials[(size_t)(64 + c) * gridDim.x + blockIdx.x] = s1;
  }
}

// ---------- fused reduce + BN finalize: block c -> scale[c], shift[c] ----------
__global__ __launch_bounds__(256) void reduce2_kernel(
    const float* __restrict__ partials, const float* __restrict__ gamma,
    const float* __restrict__ beta, float* __restrict__ scale,
    float* __restrict__ shift, int NB, int C, float invM) {
  __shared__ float l0[4], l1[4];
  const int c = blockIdx.x, tid = threadIdx.x;
  const float* p0 = partials + (size_t)c * NB;
  const float* p1 = partials + (size_t)(C + c) * NB;
  float s0 = 0.f, s1 = 0.f;
  for (int i = tid; i < NB; i += 256) { s0 += p0[i]; s1 += p1[i]; }
#pragma unroll
  for (int off = 1; off < 64; off <<= 1) {
    s0 += __shfl_xor(s0, off);
    s1 += __shfl_xor(s1, off);
  }
  if ((tid & 63) == 0) { l0[tid >> 6] = s0; l1[tid >> 6] = s1; }
  __syncthreads();
  if (tid == 0) {
    s0 = l0[0] + l0[1] + l0[2] + l0[3];
    s1 = l1[0] + l1[1] + l1[2] + l1[3];
    float mean = s0 * invM;
    float var = fmaxf(s1 * invM - mean * mean, 0.f);
    float sc = gamma[c] / sqrtf(var + 1e-5f);
    scale[c] = sc;
    shift[c] = beta[c] - mean * sc;
  }
}

// ---------- elementwise BN+ReLU apply (f16 -> f16), 8 elems/thread ----------
__global__ __launch_bounds__(256) void apply_kernel(
    const short* __restrict__ h, short* __restrict__ f,
    const float* __restrict__ scale, const float* __restrict__ shift,
    int total8, int Cmask) {
  int t = blockIdx.x * 256 + threadIdx.x;
  if (t >= total8) return;
  size_t i = (size_t)t * 8;
  int c0 = (int)(i & (size_t)Cmask);
  short8 v = *reinterpret_cast<const short8*>(h + i);
  short8 o;
#pragma unroll
  for (int j = 0; j < 8; ++j) {
    float y = h2f(v[j]) * scale[c0 + j] + shift[c0 + j];
    o[j] = f2h(fmaxf(y, 0.f));
  }
  *reinterpret_cast<short8*>(f + i) = o;
}

// ---------- farthest point sampling v5 ----------
// Tracked (value,index) argmax in the update loop (no rescan), single payload
// DPP chain per wave, winner thread deposits (v,x,y,z,idx) in its wave slot
// (coords selected from registers via uniform-index cndmask chain), all lanes
// serially combine NW slots after ONE LDS read. No point mirror in LDS, no
// dependent coord lookup. One barrier/iter (double-buffered slots).
// Exact numpy semantics: unfused fp32 distances, argmax tie -> smallest index.
template <int NPTS, int T>
__global__ __launch_bounds__(T) void fps_kernel(const float* __restrict__ xyz,
                                                int* __restrict__ out, int nsel) {
  constexpr int PT = NPTS / T;
  constexpr int NW = T / 64;
  constexpr int LOG2T = __builtin_ctz(T);
  __shared__ float4 slotA[2][NW];
  __shared__ unsigned slotI[2][NW];
  __shared__ float cinit[3];
  const int tid = threadIdx.x, b = blockIdx.x;
  const int wave = tid >> 6;
  const float* base = xyz + (size_t)b * NPTS * 3;
  float px[PT], py[PT], pz[PT], dmin[PT];
#pragma unroll
  for (int j = 0; j < PT; ++j) {
    int n = j * T + tid;
    px[j] = base[n * 3]; py[j] = base[n * 3 + 1]; pz[j] = base[n * 3 + 2];
    dmin[j] = 1e10f;
  }
  if (tid == 0) { cinit[0] = px[0]; cinit[1] = py[0]; cinit[2] = pz[0]; }
  __syncthreads();
  float cx = cinit[0], cy = cinit[1], cz = cinit[2];
  int far = 0;
  for (int it = 0; it < nsel; ++it) {
    if (tid == 0) out[b * nsel + it] = far;
    float bv = -1.f; unsigned bi = 0u;
#pragma unroll
    for (int j = 0; j < PT; ++j) {
      float dx = __fsub_rn(px[j], cx), dy = __fsub_rn(py[j], cy), dz = __fsub_rn(pz[j], cz);
      float d = __fadd_rn(__fadd_rn(__fmul_rn(dx, dx), __fmul_rn(dy, dy)), __fmul_rn(dz, dz));
      float dm = fminf(dmin[j], d);
      dmin[j] = dm;
      bool t = dm > bv;  // strict >, ascending j -> smallest index kept
      bv = t ? dm : bv;
      bi = t ? (unsigned)(j * T + tid) : bi;
    }
    wave_argmax_pay(bv, bi);
    float wmv = __builtin_bit_cast(float,
        __builtin_amdgcn_readlane(__builtin_bit_cast(int, bv), 63));
    unsigned wmi = (unsigned)__builtin_amdgcn_readlane((int)bi, 63);
    const int jsel = (int)(wmi >> LOG2T);
    float xc = px[0], yc = py[0], zc = pz[0];
#pragma unroll
    for (int j = 1; j < PT; ++j) {
      bool m = (jsel == j);
      xc = m ? px[j] : xc; yc = m ? py[j] : yc; zc = m ? pz[j] : zc;
    }
    const int bsel = it & 1;
    if (tid == (int)(wmi & (unsigned)(T - 1))) {  // exactly one thread per wave
      slotA[bsel][wave] = make_float4(wmv, xc, yc, zc);
      slotI[bsel][wave] = wmi;
    }
    __syncthreads();
    float4 bst = slotA[bsel][0];
    unsigned bI = slotI[bsel][0];
#pragma unroll
    for (int w = 1; w < NW; ++w) {
      float4 sw = slotA[bsel][w];
      unsigned iw = slotI[bsel][w];
      bool t = (sw.x > bst.x) || (sw.x == bst.x && iw < bI);
      if (t) { bst = sw; bI = iw; }
    }
    far = (int)bI;
    cx = bst.y; cy = bst.z; cz = bst.w;
  }
}

// ---------- kNN: 32 smallest (d, idx); payload DPP argmin + incremental rescan
template <int NPTS, int S>
__global__ __launch_bounds__(256) void knn_kernel(const float* __restrict__ pts,
                                                  const float* __restrict__ ctr,
                                                  int* __restrict__ knn) {
  constexpr int PT = NPTS / 256;
  __shared__ float wv[2][4];
  __shared__ unsigned widx[2][4];
  const int tid = threadIdx.x, bs = blockIdx.x;
  const int lane = tid & 63, wave = tid >> 6;
  const int b = bs / S;
  const float* base = pts + (size_t)b * NPTS * 3;
  const float qx = ctr[bs * 3], qy = ctr[bs * 3 + 1], qz = ctr[bs * 3 + 2];
  const float qq = __fadd_rn(__fadd_rn(__fmul_rn(qx, qx), __fmul_rn(qy, qy)), __fmul_rn(qz, qz));
  float d[PT];
#pragma unroll
  for (int j = 0; j < PT; ++j) {
    int n = j * 256 + tid;
    float x = base[n * 3], y = base[n * 3 + 1], z = base[n * 3 + 2];
    float pp = __fadd_rn(__fadd_rn(__fmul_rn(x, x), __fmul_rn(y, y)), __fmul_rn(z, z));
    float dot = __fadd_rn(__fadd_rn(__fmul_rn(qx, x), __fmul_rn(qy, y)), __fmul_rn(qz, z));
    d[j] = __fsub_rn(__fadd_rn(qq, pp), __fmul_rn(2.f, dot));
  }
  unsigned sel = 0;
  float bv = 3.4e38f; unsigned bi = 0xffffffffu;
#pragma unroll
  for (int j = 0; j < PT; ++j)
    if (d[j] < bv) { bv = d[j]; bi = (unsigned)(j * 256 + tid); }
  for (int k = 0; k < 32; ++k) {
    float rv = bv; unsigned ri = bi;
    wave_argmin_pay(rv, ri);
    float wmv = __builtin_bit_cast(float,
        __builtin_amdgcn_readlane(__builtin_bit_cast(int, rv), 63));
    unsigned wmi = (unsigned)__builtin_amdgcn_readlane((int)ri, 63);
    const int ksel = k & 1;
    if (lane == 0) { wv[ksel][wave] = wmv; widx[ksel][wave] = wmi; }
    __syncthreads();
    float gv = wv[ksel][0]; unsigned gi = widx[ksel][0];
#pragma unroll
    for (int w = 1; w < 4; ++w) {
      float ov = wv[ksel][w]; unsigned oi = widx[ksel][w];
      bool t = (ov < gv) || (ov == gv && oi < gi);
      gv = t ? ov : gv; gi = t ? oi : gi;
    }
    if (tid == 0) knn[(size_t)bs * 32 + k] = (int)gi;
    if ((gi & 255u) == (unsigned)tid) {  // only the winner rescans its candidates
      sel |= 1u << (gi >> 8);
      bv = 3.4e38f; bi = 0xffffffffu;
#pragma unroll
      for (int j = 0; j < PT; ++j)
        if (!((sel >> j) & 1u) && d[j] < bv) { bv = d[j]; bi = (unsigned)(j * 256 + tid); }
    }
  }
}

// ---------- gather centers: xyz + features at fps indices ----------
template <int S, int NPTS, int C>
__global__ void gather_kernel(const int* __restrict__ fps, const float* __restrict__ xyzsrc,
                              const short* __restrict__ fsrc, float* __restrict__ xyzdst,
                              short* __restrict__ fdst) {
  const int bs = blockIdx.x, tid = threadIdx.x;
  const int b = bs / S;
  const int idx = fps[bs];
  fdst[(size_t)bs * C + tid] = fsrc[((size_t)b * NPTS + idx) * C + tid];
  if (tid < 3) xyzdst[(size_t)bs * 3 + tid] = xyzsrc[((size_t)b * NPTS + idx) * 3 + tid];
}

// ---------- MFMA GEMM: [M][KD] @ [ND][KD]^T -> [M][ND] f16 + BN partials
// GATHER: A-row m=(b,s,k): first KD/2 from F[b, knn[m], :], second from FC[b, s, :]
// BNA: apply scale/shift + ReLU to A elements on load (f16 in/out)
template <int KD, int ND, bool GATHER, bool BNA, int NPTS, int S>
__global__ __launch_bounds__(256) void gemm_kernel(
    const short* A, const short* FC, const int* KNNp, const short* __restrict__ W,
    const float* __restrict__ bnscale, const float* __restrict__ bnshift,
    short* Hout, float* __restrict__ partials, int M) {
  constexpr int C = KD / 2;
  constexpr int NT = (ND > 128) ? 8 : ND / 16;
  constexpr int BR = (ND > 128) ? 64 : 128;
  constexpr int KT = KD / 32;
  __shared__ short lb[ND * 40];  // [ND][32+8] pad -> <=2-way bank alias on ds_read_b128
  __shared__ float lstats[2 * ND];
  const int tid = threadIdx.x;
  const int wave = tid >> 6, lane = tid & 63;
  const int rowOff = (ND > 128) ? (wave >> 1) * 32 : wave * 32;
  const int colOff = (ND > 128) ? (wave & 1) * 128 : 0;
  const int mBase = blockIdx.x * BR + rowOff;
  for (int i = tid; i < 2 * ND; i += 256) lstats[i] = 0.f;

  const short* aptr[2][2];
#pragma unroll
  for (int rg = 0; rg < 2; ++rg) {
    int m = mBase + rg * 16 + (lane & 15);
    if constexpr (GATHER) {
      int idx = KNNp[m];
      int bb = m / (S * 32);
      int s = (m - bb * (S * 32)) >> 5;
      aptr[rg][0] = A + ((size_t)bb * NPTS + idx) * C;
      aptr[rg][1] = FC + ((size_t)bb * S + s) * C;
    } else {
      aptr[rg][0] = A + (size_t)m * KD;
      aptr[rg][1] = A + (size_t)m * KD + C;
    }
  }
  const int koLane = (lane >> 4) * 8;
  f32x4 acc[2][NT];
#pragma unroll
  for (int rg = 0; rg < 2; ++rg)
#pragma unroll
    for (int nt = 0; nt < NT; ++nt) acc[rg][nt] = (f32x4){0.f, 0.f, 0.f, 0.f};

#pragma unroll
  for (int kt = 0; kt < KT; ++kt) {
    __syncthreads();
    constexpr int CH = (ND * 32) / 2048;
#pragma unroll
    for (int ch = 0; ch < CH; ++ch) {
      int e = ch * 2048 + tid * 8;
      int n = e >> 5, kk = e & 31;
      short8 v = *reinterpret_cast<const short8*>(W + (size_t)n * KD + kt * 32 + kk);
      *reinterpret_cast<short8*>(&lb[n * 40 + kk]) = v;
    }
    __syncthreads();
    const int half = (kt * 32 >= C) ? 1 : 0;
    const int ko = kt * 32 + koLane;
    const int koh = ko - half * C;
    short8 afrag[2];
#pragma unroll
    for (int rg = 0; rg < 2; ++rg) {
      short8 a = *reinterpret_cast<const short8*>(aptr[rg][half] + koh);
      if constexpr (BNA) {
        const float* scp = bnscale + ko;
        const float* shp = bnshift + ko;
#pragma unroll
        for (int j = 0; j < 8; ++j) {
          float v = h2f(a[j]);
          v = fmaxf(v * scp[j] + shp[j], 0.f);
          a[j] = f2h(v);
        }
      }
      afrag[rg] = a;
    }
#pragma unroll
    for (int nt = 0; nt < NT; ++nt) {
      short8 bfr = *reinterpret_cast<const short8*>(&lb[(colOff + nt * 16 + (lane & 15)) * 40 + koLane]);
      acc[0][nt] = mfma16(afrag[0], bfr, acc[0][nt]);
      acc[1][nt] = mfma16(afrag[1], bfr, acc[1][nt]);
    }
  }
  __syncthreads();  // all A-reads done before in-place stores (ND=256 waves share rows)

  // per-channel sum / sumsq partials
#pragma unroll
  for (int nt = 0; nt < NT; ++nt) {
    float s0 = 0.f, s1 = 0.f;
#pragma unroll
    for (int rg = 0; rg < 2; ++rg)
#pragma unroll
      for (int i = 0; i < 4; ++i) {
        float v = acc[rg][nt][i];
        s0 += v; s1 += v * v;
      }
    s0 += __shfl_xor(s0, 16); s0 += __shfl_xor(s0, 32);
    s1 += __shfl_xor(s1, 16); s1 += __shfl_xor(s1, 32);
    if (lane < 16) {
      atomicAdd(&lstats[colOff + nt * 16 + lane], s0);
      atomicAdd(&lstats[ND + colOff + nt * 16 + lane], s1);
    }
  }
  // store output (C/D layout: row = 4*(lane>>4)+i, col = lane&15)
#pragma unroll
  for (int rg = 0; rg < 2; ++rg)
#pragma unroll
    for (int nt = 0; nt < NT; ++nt)
#pragma unroll
      for (int i = 0; i < 4; ++i) {
        int m2 = mBase + rg * 16 + (lane >> 4) * 4 + i;
        int n = colOff + nt * 16 + (lane & 15);
        Hout[(size_t)m2 * ND + n] = f2h(acc[rg][nt][i]);
      }
  __syncthreads();
  for (int i = tid; i < 2 * ND; i += 256)
    partials[(size_t)i * gridDim.x + blockIdx.x] = lstats[i];
}

// ---------- max over K with BN+ReLU -> f1 f16 ----------
__global__ __launch_bounds__(128) void maxpool_f1_kernel(
    const short* __restrict__ h, const float* __restrict__ scale,
    const float* __restrict__ shift, short* __restrict__ f1) {
  const int bs = blockIdx.x, c = threadIdx.x;
  const float sc = scale[c], sh = shift[c];
  float m = 0.f;  // relu outputs >= 0
  for (int k = 0; k < 32; ++k) {
    float v = h2f(h[((size_t)bs * 32 + k) * 128 + c]);
    m = fmaxf(m, fmaxf(v * sc + sh, 0.f));
  }
  f1[(size_t)bs * 128 + c] = f2h(m);
}

// ---------- final: max over K with BN+ReLU, transposed fp32 out [B][C][S] ----------
__global__ __launch_bounds__(256) void maxpool_out_kernel(
    const short* __restrict__ h, const float* __restrict__ scale,
    const float* __restrict__ shift, float* __restrict__ out) {
  const int bs = blockIdx.x, c = threadIdx.x;
  const int b = bs >> 8, s = bs & 255;
  const float sc = scale[c], sh = shift[c];
  float m = 0.f;
  for (int k = 0; k < 32; ++k) {
    float v = h2f(h[((size_t)bs * 32 + k) * 256 + c]);
    m = fmaxf(m, fmaxf(v * sc + sh, 0.f));
  }
  out[((size_t)b << 16) + ((size_t)c << 8) + s] = m;
}

// ---------- launch ----------
extern "C" void kernel_launch(void* const* d_in, const int* in_sizes, int n_in,
                              void* d_out, int out_size, void* d_ws, size_t ws_size,
                              hipStream_t stream) {
  (void)in_sizes; (void)n_in; (void)out_size; (void)ws_size;
  const float* x    = (const float*)d_in[0];
  const float* w1   = (const float*)d_in[1];
  const float* g1   = (const float*)d_in[2];
  const float* b1   = (const float*)d_in[3];
  const float* w2   = (const float*)d_in[4];
  const float* g2   = (const float*)d_in[5];
  const float* b2   = (const float*)d_in[6];
  const float* s1w1 = (const float*)d_in[7];
  const float* s1g1 = (const float*)d_in[8];
  const float* s1b1 = (const float*)d_in[9];
  const float* s1w2 = (const float*)d_in[10];
  const float* s1g2 = (const float*)d_in[11];
  const float* s1b2 = (const float*)d_in[12];
  const float* s2w1 = (const float*)d_in[13];
  const float* s2g1 = (const float*)d_in[14];
  const float* s2b1 = (const float*)d_in[15];
  const float* s2w2 = (const float*)d_in[16];
  const float* s2g2 = (const float*)d_in[17];
  const float* s2b2 = (const float*)d_in[18];
  float* out = (float*)d_out;

  char* ws = (char*)d_ws;
  size_t off = 0;
  auto alloc = [&](size_t bytes) -> char* {
    size_t p = (off + 255) & ~(size_t)255;
    off = p + bytes;
    return ws + p;
  };

  float* xyz      = (float*)alloc(32ull * 4096 * 3 * 4);
  short* h0       = (short*)alloc(32ull * 4096 * 64 * 2);
  short* hb       = (short*)alloc(32ull * 4096 * 64 * 2);
  short* fb       = (short*)alloc(32ull * 4096 * 64 * 2);
  int*   fps1     = (int*)alloc(32ull * 512 * 4);
  float* xyzc1    = (float*)alloc(32ull * 512 * 3 * 4);
  short* fcen1    = (short*)alloc(32ull * 512 * 64 * 2);
  int*   knn1     = (int*)alloc(32ull * 512 * 32 * 4);
  short* f1       = (short*)alloc(32ull * 512 * 128 * 2);
  int*   fps2     = (int*)alloc(32ull * 256 * 4);
  float* xyzc2    = (float*)alloc(32ull * 256 * 3 * 4);
  short* fcen2    = (short*)alloc(32ull * 256 * 128 * 2);
  int*   knn2     = (int*)alloc(32ull * 256 * 32 * 4);
  short* hbuf     = (short*)alloc(134217728ull);          // shared SG1/SG2 h buffer
  float* partials = (float*)alloc(2ull * 256 * 4096 * 4); // 8 MB
  float* scA  = (float*)alloc(64 * 4);  float* shA  = (float*)alloc(64 * 4);
  float* scBc = (float*)alloc(64 * 4);  float* shBc = (float*)alloc(64 * 4);
  float* sc1a = (float*)alloc(128 * 4); float* sh1a = (float*)alloc(128 * 4);
  float* sc1b = (float*)alloc(128 * 4); float* sh1b = (float*)alloc(128 * 4);
  float* sc2a = (float*)alloc(256 * 4); float* sh2a = (float*)alloc(256 * 4);
  float* sc2b = (float*)alloc(256 * 4); float* sh2b = (float*)alloc(256 * 4);
  short* w2b   = (short*)alloc(4096 * 2);
  short* s1w2b = (short*)alloc(16384 * 2);
  short* s2w2b = (short*)alloc(65536 * 2);
  short* W1pp  = (short*)alloc(16384 * 2);
  short* W2pp  = (short*)alloc(65536 * 2);

  prep_kernel<<<656, 256, 0, stream>>>(w2, s1w2, s2w2, s1w1, s2w1, w2b, s1w2b, s2w2b, W1pp, W2pp);
  stageA_kernel<<<512, 256, 0, stream>>>(x, w1, xyz, h0);
  stats64_kernel<<<256, 256, 0, stream>>>(h0, partials, 131072);
  reduce2_kernel<<<64, 256, 0, stream>>>(partials, g1, b1, scA, shA, 256, 64, 1.f / 131072.f);
  gemm_kernel<64, 64, false, true, 1, 1><<<1024, 256, 0, stream>>>(
      h0, nullptr, nullptr, w2b, scA, shA, hb, partials, 131072);
  reduce2_kernel<<<64, 256, 0, stream>>>(partials, g2, b2, scBc, shBc, 1024, 64, 1.f / 131072.f);
  apply_kernel<<<4096, 256, 0, stream>>>(hb, fb, scBc, shBc, 1048576, 63);

  fps_kernel<4096, 512><<<32, 512, 0, stream>>>(xyz, fps1, 512);
  gather_kernel<512, 4096, 64><<<16384, 64, 0, stream>>>(fps1, xyz, fb, xyzc1, fcen1);
  knn_kernel<4096, 512><<<16384, 256, 0, stream>>>(xyz, xyzc1, knn1);

  gemm_kernel<128, 128, true, false, 4096, 512><<<4096, 256, 0, stream>>>(
      fb, fcen1, knn1, W1pp, nullptr, nullptr, hbuf, partials, 524288);
  reduce2_kernel<<<128, 256, 0, stream>>>(partials, s1g1, s1b1, sc1a, sh1a, 4096, 128, 1.f / 524288.f);
  gemm_kernel<128, 128, false, true, 1, 1><<<4096, 256, 0, stream>>>(
      hbuf, nullptr, nullptr, s1w2b, sc1a, sh1a, hbuf, partials, 524288);
  reduce2_kernel<<<128, 256, 0, stream>>>(partials, s1g2, s1b2, sc1b, sh1b, 4096, 128, 1.f / 524288.f);
  maxpool_f1_kernel<<<16384, 128, 0, stream>>>(hbuf, sc1b, sh1b, f1);

  fps_kernel<512, 512><<<32, 512, 0, stream>>>(xyzc1, fps2, 256);
  gather_kernel<256, 512, 128><<<8192, 128, 0, stream>>>(fps2, xyzc1, f1, xyzc2, fcen2);
  knn_kernel<512, 256><<<8192, 256, 0, stream>>>(xyzc1, xyzc2, knn2);

  gemm_kernel<256, 256, true, false, 512, 256><<<4096, 256, 0, stream>>>(
      f1, fcen2, knn2, W2pp, nullptr, nullptr, hbuf, partials, 262144);
  reduce2_kernel<<<256, 256, 0, stream>>>(partials, s2g1, s2b1, sc2a, sh2a, 4096, 256, 1.f / 262144.f);
  gemm_kernel<256, 256, false, true, 1, 1><<<4096, 256, 0, stream>>>(
      hbuf, nullptr, nullptr, s2w2b, sc2a, sh2a, hbuf, partials, 262144);
  reduce2_kernel<<<256, 256, 0, stream>>>(partials, s2g2, s2b2, sc2b, sh2b, 4096, 256, 1.f / 262144.f);
  maxpool_out_kernel<<<8192, 256, 0, stream>>>(hbuf, sc2b, sh2b, out);
}

// Round 7
// 1458.103 us; speedup vs baseline: 1.5006x; 1.5006x over previous
//
#include <hip/hip_runtime.h>

// ---------- types & helpers ----------
typedef short short8 __attribute__((ext_vector_type(8)));
typedef _Float16 h8 __attribute__((ext_vector_type(8)));
typedef float f32x4 __attribute__((ext_vector_type(4)));

#define DEVI __device__ __forceinline__

DEVI float h2f(short s) { return (float)__builtin_bit_cast(_Float16, s); }
DEVI short f2h(float f) { return __builtin_bit_cast(short, (_Float16)f); }
DEVI f32x4 mfma16(short8 a, short8 b, f32x4 c) {
  return __builtin_amdgcn_mfma_f32_16x16x32_f16(
      __builtin_bit_cast(h8, a), __builtin_bit_cast(h8, b), c, 0, 0, 0);
}

// ---------- DPP 64-lane reductions (gfx9 pattern), result broadcast ----------
// Value-only chains fuse to one VOP per step (v_max_f32 dst, dpp(src), dst).
DEVI float wave_max_bcast(float v) {
  const int ID = 0xff800000;  // -inf
  int x = __builtin_bit_cast(int, v);
#define STEPM(ctrl)                                                     \
  {                                                                     \
    int t = __builtin_amdgcn_update_dpp(ID, x, ctrl, 0xf, 0xf, false);  \
    x = __builtin_bit_cast(int, fmaxf(__builtin_bit_cast(float, x),     \
                                      __builtin_bit_cast(float, t)));   \
  }
  STEPM(0x111) STEPM(0x112) STEPM(0x114) STEPM(0x118) STEPM(0x142) STEPM(0x143)
#undef STEPM
  return __builtin_bit_cast(float, __builtin_amdgcn_readlane(x, 63));
}
DEVI float wave_min_bcast_f(float v) {
  const int ID = 0x7f800000;  // +inf
  int x = __builtin_bit_cast(int, v);
#define STEPN(ctrl)                                                     \
  {                                                                     \
    int t = __builtin_amdgcn_update_dpp(ID, x, ctrl, 0xf, 0xf, false);  \
    x = __builtin_bit_cast(int, fminf(__builtin_bit_cast(float, x),     \
                                      __builtin_bit_cast(float, t)));   \
  }
  STEPN(0x111) STEPN(0x112) STEPN(0x114) STEPN(0x118) STEPN(0x142) STEPN(0x143)
#undef STEPN
  return __builtin_bit_cast(float, __builtin_amdgcn_readlane(x, 63));
}
DEVI unsigned wave_min_bcast_u(unsigned v) {
  const int ID = (int)0xffffffff;
  int x = (int)v;
#define STEPU(ctrl)                                                     \
  {                                                                     \
    int t = __builtin_amdgcn_update_dpp(ID, x, ctrl, 0xf, 0xf, false);  \
    x = (int)((unsigned)x < (unsigned)t ? (unsigned)x : (unsigned)t);   \
  }
  STEPU(0x111) STEPU(0x112) STEPU(0x114) STEPU(0x118) STEPU(0x142) STEPU(0x143)
#undef STEPU
  return (unsigned)__builtin_amdgcn_readlane(x, 63);
}

// ---------- weight prep: f16 casts + folded W'' = [w1a | w1b - w1a] ----------
__global__ __launch_bounds__(256) void prep_kernel(
    const float* __restrict__ w2, const float* __restrict__ s1w2,
    const float* __restrict__ s2w2, const float* __restrict__ s1w1,
    const float* __restrict__ s2w1, short* __restrict__ w2b,
    short* __restrict__ s1w2b, short* __restrict__ s2w2b,
    short* __restrict__ W1pp, short* __restrict__ W2pp) {
  int i = blockIdx.x * 256 + threadIdx.x;
  if (i < 4096) {
    w2b[i] = f2h(w2[i]);
  } else if (i < 20480) {
    int j = i - 4096; s1w2b[j] = f2h(s1w2[j]);
  } else if (i < 86016) {
    int j = i - 20480; s2w2b[j] = f2h(s2w2[j]);
  } else if (i < 102400) {
    int j = i - 86016; int c = j & 127;
    float v = s1w1[j]; if (c >= 64) v -= s1w1[j - 64];
    W1pp[j] = f2h(v);
  } else if (i < 167936) {
    int j = i - 102400; int c = j & 255;
    float v = s2w1[j]; if (c >= 128) v -= s2w1[j - 128];
    W2pp[j] = f2h(v);
  }
}

// ---------- stage A: xyz transpose + h0 = x @ w1^T (K=3, VALU fp32) ----------
__global__ __launch_bounds__(256) void stageA_kernel(
    const float* __restrict__ x, const float* __restrict__ w1,
    float* __restrict__ xyz, short* __restrict__ h0) {
  int i = blockIdx.x * 256 + threadIdx.x;  // b*4096 + n, < 131072
  int b = i >> 12, n = i & 4095;
  const float* xb = x + ((size_t)b * 3 << 12) + n;
  float x0 = xb[0], x1 = xb[4096], x2 = xb[8192];
  float* xp = xyz + (size_t)i * 3;
  xp[0] = x0; xp[1] = x1; xp[2] = x2;
  short* hp = h0 + ((size_t)i << 6);
#pragma unroll
  for (int o8 = 0; o8 < 8; ++o8) {
    short8 t;
#pragma unroll
    for (int j = 0; j < 8; ++j) {
      int o = o8 * 8 + j;
      float h = x0 * w1[o * 3] + x1 * w1[o * 3 + 1] + x2 * w1[o * 3 + 2];
      t[j] = f2h(h);
    }
    *reinterpret_cast<short8*>(hp + o8 * 8) = t;
  }
}

// ---------- channel stats for a [M][64] f16 tensor -> transposed partials ----------
__global__ __launch_bounds__(256) void stats64_kernel(
    const short* __restrict__ h, float* __restrict__ partials, int M) {
  __shared__ float l0[256], l1[256];
  const int tid = threadIdx.x;
  const int c = tid & 63, g = tid >> 6;
  float s0 = 0.f, s1 = 0.f;
  for (int m = blockIdx.x * 4 + g; m < M; m += gridDim.x * 4) {
    float v = h2f(h[(size_t)m * 64 + c]);
    s0 += v; s1 += v * v;
  }
  l0[tid] = s0; l1[tid] = s1;
  __syncthreads();
  if (g == 0) {
    for (int w = 1; w < 4; ++w) { s0 += l0[c + w * 64]; s1 += l1[c + w * 64]; }
    partials[(size_t)c * gridDim.x + blockIdx.x] = s0;
    partials[(size_t)(64 + c) * gridDim.x + blockIdx.x] = s1;
  }
}

// ---------- fused reduce + BN finalize: block c -> scale[c], shift[c] ----------
__global__ __launch_bounds__(256) void reduce2_kernel(
    const float* __restrict__ partials, const float* __restrict__ gamma,
    const float* __restrict__ beta, float* __restrict__ scale,
    float* __restrict__ shift, int NB, int C, float invM) {
  __shared__ float l0[4], l1[4];
  const int c = blockIdx.x, tid = threadIdx.x;
  const float* p0 = partials + (size_t)c * NB;
  const float* p1 = partials + (size_t)(C + c) * NB;
  float s0 = 0.f, s1 = 0.f;
  for (int i = tid; i < NB; i += 256) { s0 += p0[i]; s1 += p1[i]; }
#pragma unroll
  for (int off = 1; off < 64; off <<= 1) {
    s0 += __shfl_xor(s0, off);
    s1 += __shfl_xor(s1, off);
  }
  if ((tid & 63) == 0) { l0[tid >> 6] = s0; l1[tid >> 6] = s1; }
  __syncthreads();
  if (tid == 0) {
    s0 = l0[0] + l0[1] + l0[2] + l0[3];
    s1 = l1[0] + l1[1] + l1[2] + l1[3];
    float mean = s0 * invM;
    float var = fmaxf(s1 * invM - mean * mean, 0.f);
    float sc = gamma[c] / sqrtf(var + 1e-5f);
    scale[c] = sc;
    shift[c] = beta[c] - mean * sc;
  }
}

// ---------- elementwise BN+ReLU apply (f16 -> f16), 8 elems/thread ----------
__global__ __launch_bounds__(256) void apply_kernel(
    const short* __restrict__ h, short* __restrict__ f,
    const float* __restrict__ scale, const float* __restrict__ shift,
    int total8, int Cmask) {
  int t = blockIdx.x * 256 + threadIdx.x;
  if (t >= total8) return;
  size_t i = (size_t)t * 8;
  int c0 = (int)(i & (size_t)Cmask);
  short8 v = *reinterpret_cast<const short8*>(h + i);
  short8 o;
#pragma unroll
  for (int j = 0; j < 8; ++j) {
    float y = h2f(v[j]) * scale[c0 + j] + shift[c0 + j];
    o[j] = f2h(fmaxf(y, 0.f));
  }
  *reinterpret_cast<short8*>(f + i) = o;
}

// ---------- farthest point sampling (v4 structure, restored) ----------
// T=256 (4 waves, 1/SIMD): value-only fmin/fmax update; index rescan; fused
// DPP value chains; per-wave slot; serial 4-slot combine; coords via one
// broadcast LDS read from the point mirror. __launch_bounds__(T,1) gives the
// full VGPR budget (v5's spill: VGPR=40 -> scratch thrash, 786us + 31ms outlier).
// Exact numpy semantics: unfused fp32 distances, argmax tie -> smallest index.
template <int NPTS, int T>
__global__ __launch_bounds__(T, 1) void fps_kernel(const float* __restrict__ xyz,
                                                   int* __restrict__ out, int nsel) {
  constexpr int PT = NPTS / T;
  constexpr int NW = T / 64;
  __shared__ float sx[NPTS], sy[NPTS], sz[NPTS];
  __shared__ float wv[2][NW];
  __shared__ unsigned wi[2][NW];
  const int tid = threadIdx.x, b = blockIdx.x;
  const int lane = tid & 63, wave = tid >> 6;
  const float* base = xyz + (size_t)b * NPTS * 3;
  float px[PT], py[PT], pz[PT], dmin[PT];
#pragma unroll
  for (int j = 0; j < PT; ++j) {
    int n = j * T + tid;
    px[j] = base[n * 3]; py[j] = base[n * 3 + 1]; pz[j] = base[n * 3 + 2];
    sx[n] = px[j]; sy[n] = py[j]; sz[n] = pz[j];
    dmin[j] = 1e10f;
  }
  __syncthreads();
  int far = 0;
  float cx = sx[0], cy = sy[0], cz = sz[0];
  for (int it = 0; it < nsel; ++it) {
    if (tid == 0) out[b * nsel + it] = far;
    float bv = -1.f;
#pragma unroll
    for (int j = 0; j < PT; ++j) {
      float dx = __fsub_rn(px[j], cx), dy = __fsub_rn(py[j], cy), dz = __fsub_rn(pz[j], cz);
      float d = __fadd_rn(__fadd_rn(__fmul_rn(dx, dx), __fmul_rn(dy, dy)), __fmul_rn(dz, dz));
      float dm = fminf(dmin[j], d);
      dmin[j] = dm;
      bv = fmaxf(bv, dm);
    }
    float wmv = wave_max_bcast(bv);
    // rescan (descending j so the LAST write = smallest index)
    unsigned ci = 0xffffffffu;
#pragma unroll
    for (int j = PT - 1; j >= 0; --j)
      if (dmin[j] == wmv) ci = (unsigned)(j * T + tid);
    unsigned wmi = wave_min_bcast_u(ci);
    const int bsel = it & 1;
    if (lane == 0) { wv[bsel][wave] = wmv; wi[bsel][wave] = wmi; }
    __syncthreads();
    // lane-parallel cross-wave combine: lane reads slot (lane & (NW-1)),
    // then log2(NW) DPP row_ror steps carrying (v, idx).
    const int e = lane & (NW - 1);
    float v = wv[bsel][e];
    unsigned si = wi[bsel][e];
#define CMB(ctrl)                                                                        \
  {                                                                                      \
    float v2 = __builtin_bit_cast(                                                       \
        float, __builtin_amdgcn_update_dpp(0, __builtin_bit_cast(int, v), ctrl, 0xf, 0xf, true)); \
    unsigned i2 = (unsigned)__builtin_amdgcn_update_dpp(0, (int)si, ctrl, 0xf, 0xf, true);\
    bool bt = (v2 > v) || (v2 == v && i2 < si);                                          \
    v = bt ? v2 : v; si = bt ? i2 : si;                                                  \
  }
    if constexpr (NW >= 2) CMB(0x121)   // row_ror:1
    if constexpr (NW >= 4) CMB(0x122)   // row_ror:2
    if constexpr (NW >= 8) CMB(0x124)   // row_ror:4
    if constexpr (NW >= 16) CMB(0x128)  // row_ror:8
#undef CMB
    far = (int)si;
    cx = sx[far]; cy = sy[far]; cz = sz[far];  // broadcast LDS read, once/iter
  }
}

// ---------- kNN: 32 smallest (d, idx); fused DPP chains + incremental rescan
template <int NPTS, int S>
__global__ __launch_bounds__(256) void knn_kernel(const float* __restrict__ pts,
                                                  const float* __restrict__ ctr,
                                                  int* __restrict__ knn) {
  constexpr int PT = NPTS / 256;
  __shared__ float wv[2][4];
  __shared__ unsigned wi[2][4];
  const int tid = threadIdx.x, bs = blockIdx.x;
  const int lane = tid & 63, wave = tid >> 6;
  const int b = bs / S;
  const float* base = pts + (size_t)b * NPTS * 3;
  const float qx = ctr[bs * 3], qy = ctr[bs * 3 + 1], qz = ctr[bs * 3 + 2];
  const float qq = __fadd_rn(__fadd_rn(__fmul_rn(qx, qx), __fmul_rn(qy, qy)), __fmul_rn(qz, qz));
  float d[PT];
#pragma unroll
  for (int j = 0; j < PT; ++j) {
    int n = j * 256 + tid;
    float x = base[n * 3], y = base[n * 3 + 1], z = base[n * 3 + 2];
    float pp = __fadd_rn(__fadd_rn(__fmul_rn(x, x), __fmul_rn(y, y)), __fmul_rn(z, z));
    float dot = __fadd_rn(__fadd_rn(__fmul_rn(qx, x), __fmul_rn(qy, y)), __fmul_rn(qz, z));
    d[j] = __fsub_rn(__fadd_rn(qq, pp), __fmul_rn(2.f, dot));
  }
  unsigned sel = 0;
  float bv = 3.4e38f; unsigned bi = 0x7fffffffu;
#pragma unroll
  for (int j = 0; j < PT; ++j)
    if (d[j] < bv) { bv = d[j]; bi = (unsigned)(j * 256 + tid); }
  for (int k = 0; k < 32; ++k) {
    float wmv = wave_min_bcast_f(bv);
    unsigned ci = (bv == wmv) ? bi : 0x7fffffffu;
    unsigned wmi = wave_min_bcast_u(ci);
    if (lane == 0) { wv[k & 1][wave] = wmv; wi[k & 1][wave] = wmi; }
    __syncthreads();
    float gv = wv[k & 1][0]; unsigned gi = wi[k & 1][0];
#pragma unroll
    for (int w = 1; w < 4; ++w) {
      float ov = wv[k & 1][w]; unsigned oi = wi[k & 1][w];
      bool t = (ov < gv) || (ov == gv && oi < gi);
      gv = t ? ov : gv; gi = t ? oi : gi;
    }
    if (tid == 0) knn[(size_t)bs * 32 + k] = (int)gi;
    if ((gi & 255u) == (unsigned)tid) {  // only the winner rescans its candidates
      sel |= 1u << (gi >> 8);
      bv = 3.4e38f; bi = 0x7fffffffu;
#pragma unroll
      for (int j = 0; j < PT; ++j)
        if (!((sel >> j) & 1u) && d[j] < bv) { bv = d[j]; bi = (unsigned)(j * 256 + tid); }
    }
  }
}

// ---------- gather centers: xyz + features at fps indices ----------
template <int S, int NPTS, int C>
__global__ void gather_kernel(const int* __restrict__ fps, const float* __restrict__ xyzsrc,
                              const short* __restrict__ fsrc, float* __restrict__ xyzdst,
                              short* __restrict__ fdst) {
  const int bs = blockIdx.x, tid = threadIdx.x;
  const int b = bs / S;
  const int idx = fps[bs];
  fdst[(size_t)bs * C + tid] = fsrc[((size_t)b * NPTS + idx) * C + tid];
  if (tid < 3) xyzdst[(size_t)bs * 3 + tid] = xyzsrc[((size_t)b * NPTS + idx) * 3 + tid];
}

// ---------- MFMA GEMM: [M][KD] @ [ND][KD]^T -> [M][ND] f16 + BN partials
// GATHER: A-row m=(b,s,k): first KD/2 from F[b, knn[m], :], second from FC[b, s, :]
// BNA: apply scale/shift + ReLU to A elements on load (f16 in/out)
template <int KD, int ND, bool GATHER, bool BNA, int NPTS, int S>
__global__ __launch_bounds__(256) void gemm_kernel(
    const short* A, const short* FC, const int* KNNp, const short* __restrict__ W,
    const float* __restrict__ bnscale, const float* __restrict__ bnshift,
    short* Hout, float* __restrict__ partials, int M) {
  constexpr int C = KD / 2;
  constexpr int NT = (ND > 128) ? 8 : ND / 16;
  constexpr int BR = (ND > 128) ? 64 : 128;
  constexpr int KT = KD / 32;
  __shared__ short lb[ND * 40];  // [ND][32+8] pad -> <=2-way bank alias on ds_read_b128
  __shared__ float lstats[2 * ND];
  const int tid = threadIdx.x;
  const int wave = tid >> 6, lane = tid & 63;
  const int rowOff = (ND > 128) ? (wave >> 1) * 32 : wave * 32;
  const int colOff = (ND > 128) ? (wave & 1) * 128 : 0;
  const int mBase = blockIdx.x * BR + rowOff;
  for (int i = tid; i < 2 * ND; i += 256) lstats[i] = 0.f;

  const short* aptr[2][2];
#pragma unroll
  for (int rg = 0; rg < 2; ++rg) {
    int m = mBase + rg * 16 + (lane & 15);
    if constexpr (GATHER) {
      int idx = KNNp[m];
      int bb = m / (S * 32);
      int s = (m - bb * (S * 32)) >> 5;
      aptr[rg][0] = A + ((size_t)bb * NPTS + idx) * C;
      aptr[rg][1] = FC + ((size_t)bb * S + s) * C;
    } else {
      aptr[rg][0] = A + (size_t)m * KD;
      aptr[rg][1] = A + (size_t)m * KD + C;
    }
  }
  const int koLane = (lane >> 4) * 8;
  f32x4 acc[2][NT];
#pragma unroll
  for (int rg = 0; rg < 2; ++rg)
#pragma unroll
    for (int nt = 0; nt < NT; ++nt) acc[rg][nt] = (f32x4){0.f, 0.f, 0.f, 0.f};

#pragma unroll
  for (int kt = 0; kt < KT; ++kt) {
    __syncthreads();
    constexpr int CH = (ND * 32) / 2048;
#pragma unroll
    for (int ch = 0; ch < CH; ++ch) {
      int e = ch * 2048 + tid * 8;
      int n = e >> 5, kk = e & 31;
      short8 v = *reinterpret_cast<const short8*>(W + (size_t)n * KD + kt * 32 + kk);
      *reinterpret_cast<short8*>(&lb[n * 40 + kk]) = v;
    }
    __syncthreads();
    const int half = (kt * 32 >= C) ? 1 : 0;
    const int ko = kt * 32 + koLane;
    const int koh = ko - half * C;
    short8 afrag[2];
#pragma unroll
    for (int rg = 0; rg < 2; ++rg) {
      short8 a = *reinterpret_cast<const short8*>(aptr[rg][half] + koh);
      if constexpr (BNA) {
        const float* scp = bnscale + ko;
        const float* shp = bnshift + ko;
#pragma unroll
        for (int j = 0; j < 8; ++j) {
          float v = h2f(a[j]);
          v = fmaxf(v * scp[j] + shp[j], 0.f);
          a[j] = f2h(v);
        }
      }
      afrag[rg] = a;
    }
#pragma unroll
    for (int nt = 0; nt < NT; ++nt) {
      short8 bfr = *reinterpret_cast<const short8*>(&lb[(colOff + nt * 16 + (lane & 15)) * 40 + koLane]);
      acc[0][nt] = mfma16(afrag[0], bfr, acc[0][nt]);
      acc[1][nt] = mfma16(afrag[1], bfr, acc[1][nt]);
    }
  }
  __syncthreads();  // all A-reads done before in-place stores (ND=256 waves share rows)

  // per-channel sum / sumsq partials
#pragma unroll
  for (int nt = 0; nt < NT; ++nt) {
    float s0 = 0.f, s1 = 0.f;
#pragma unroll
    for (int rg = 0; rg < 2; ++rg)
#pragma unroll
      for (int i = 0; i < 4; ++i) {
        float v = acc[rg][nt][i];
        s0 += v; s1 += v * v;
      }
    s0 += __shfl_xor(s0, 16); s0 += __shfl_xor(s0, 32);
    s1 += __shfl_xor(s1, 16); s1 += __shfl_xor(s1, 32);
    if (lane < 16) {
      atomicAdd(&lstats[colOff + nt * 16 + lane], s0);
      atomicAdd(&lstats[ND + colOff + nt * 16 + lane], s1);
    }
  }
  // store output (C/D layout: row = 4*(lane>>4)+i, col = lane&15)
#pragma unroll
  for (int rg = 0; rg < 2; ++rg)
#pragma unroll
    for (int nt = 0; nt < NT; ++nt)
#pragma unroll
      for (int i = 0; i < 4; ++i) {
        int m2 = mBase + rg * 16 + (lane >> 4) * 4 + i;
        int n = colOff + nt * 16 + (lane & 15);
        Hout[(size_t)m2 * ND + n] = f2h(acc[rg][nt][i]);
      }
  __syncthreads();
  for (int i = tid; i < 2 * ND; i += 256)
    partials[(size_t)i * gridDim.x + blockIdx.x] = lstats[i];
}

// ---------- max over K with BN+ReLU -> f1 f16 ----------
__global__ __launch_bounds__(128) void maxpool_f1_kernel(
    const short* __restrict__ h, const float* __restrict__ scale,
    const float* __restrict__ shift, short* __restrict__ f1) {
  const int bs = blockIdx.x, c = threadIdx.x;
  const float sc = scale[c], sh = shift[c];
  float m = 0.f;  // relu outputs >= 0
  for (int k = 0; k < 32; ++k) {
    float v = h2f(h[((size_t)bs * 32 + k) * 128 + c]);
    m = fmaxf(m, fmaxf(v * sc + sh, 0.f));
  }
  f1[(size_t)bs * 128 + c] = f2h(m);
}

// ---------- final: max over K with BN+ReLU, transposed fp32 out [B][C][S] ----------
__global__ __launch_bounds__(256) void maxpool_out_kernel(
    const short* __restrict__ h, const float* __restrict__ scale,
    const float* __restrict__ shift, float* __restrict__ out) {
  const int bs = blockIdx.x, c = threadIdx.x;
  const int b = bs >> 8, s = bs & 255;
  const float sc = scale[c], sh = shift[c];
  float m = 0.f;
  for (int k = 0; k < 32; ++k) {
    float v = h2f(h[((size_t)bs * 32 + k) * 256 + c]);
    m = fmaxf(m, fmaxf(v * sc + sh, 0.f));
  }
  out[((size_t)b << 16) + ((size_t)c << 8) + s] = m;
}

// ---------- launch ----------
extern "C" void kernel_launch(void* const* d_in, const int* in_sizes, int n_in,
                              void* d_out, int out_size, void* d_ws, size_t ws_size,
                              hipStream_t stream) {
  (void)in_sizes; (void)n_in; (void)out_size; (void)ws_size;
  const float* x    = (const float*)d_in[0];
  const float* w1   = (const float*)d_in[1];
  const float* g1   = (const float*)d_in[2];
  const float* b1   = (const float*)d_in[3];
  const float* w2   = (const float*)d_in[4];
  const float* g2   = (const float*)d_in[5];
  const float* b2   = (const float*)d_in[6];
  const float* s1w1 = (const float*)d_in[7];
  const float* s1g1 = (const float*)d_in[8];
  const float* s1b1 = (const float*)d_in[9];
  const float* s1w2 = (const float*)d_in[10];
  const float* s1g2 = (const float*)d_in[11];
  const float* s1b2 = (const float*)d_in[12];
  const float* s2w1 = (const float*)d_in[13];
  const float* s2g1 = (const float*)d_in[14];
  const float* s2b1 = (const float*)d_in[15];
  const float* s2w2 = (const float*)d_in[16];
  const float* s2g2 = (const float*)d_in[17];
  const float* s2b2 = (const float*)d_in[18];
  float* out = (float*)d_out;

  char* ws = (char*)d_ws;
  size_t off = 0;
  auto alloc = [&](size_t bytes) -> char* {
    size_t p = (off + 255) & ~(size_t)255;
    off = p + bytes;
    return ws + p;
  };

  float* xyz      = (float*)alloc(32ull * 4096 * 3 * 4);
  short* h0       = (short*)alloc(32ull * 4096 * 64 * 2);
  short* hb       = (short*)alloc(32ull * 4096 * 64 * 2);
  short* fb       = (short*)alloc(32ull * 4096 * 64 * 2);
  int*   fps1     = (int*)alloc(32ull * 512 * 4);
  float* xyzc1    = (float*)alloc(32ull * 512 * 3 * 4);
  short* fcen1    = (short*)alloc(32ull * 512 * 64 * 2);
  int*   knn1     = (int*)alloc(32ull * 512 * 32 * 4);
  short* f1       = (short*)alloc(32ull * 512 * 128 * 2);
  int*   fps2     = (int*)alloc(32ull * 256 * 4);
  float* xyzc2    = (float*)alloc(32ull * 256 * 3 * 4);
  short* fcen2    = (short*)alloc(32ull * 256 * 128 * 2);
  int*   knn2     = (int*)alloc(32ull * 256 * 32 * 4);
  short* hbuf     = (short*)alloc(134217728ull);          // shared SG1/SG2 h buffer
  float* partials = (float*)alloc(2ull * 256 * 4096 * 4); // 8 MB
  float* scA  = (float*)alloc(64 * 4);  float* shA  = (float*)alloc(64 * 4);
  float* scBc = (float*)alloc(64 * 4);  float* shBc = (float*)alloc(64 * 4);
  float* sc1a = (float*)alloc(128 * 4); float* sh1a = (float*)alloc(128 * 4);
  float* sc1b = (float*)alloc(128 * 4); float* sh1b = (float*)alloc(128 * 4);
  float* sc2a = (float*)alloc(256 * 4); float* sh2a = (float*)alloc(256 * 4);
  float* sc2b = (float*)alloc(256 * 4); float* sh2b = (float*)alloc(256 * 4);
  short* w2b   = (short*)alloc(4096 * 2);
  short* s1w2b = (short*)alloc(16384 * 2);
  short* s2w2b = (short*)alloc(65536 * 2);
  short* W1pp  = (short*)alloc(16384 * 2);
  short* W2pp  = (short*)alloc(65536 * 2);

  prep_kernel<<<656, 256, 0, stream>>>(w2, s1w2, s2w2, s1w1, s2w1, w2b, s1w2b, s2w2b, W1pp, W2pp);
  stageA_kernel<<<512, 256, 0, stream>>>(x, w1, xyz, h0);
  stats64_kernel<<<256, 256, 0, stream>>>(h0, partials, 131072);
  reduce2_kernel<<<64, 256, 0, stream>>>(partials, g1, b1, scA, shA, 256, 64, 1.f / 131072.f);
  gemm_kernel<64, 64, false, true, 1, 1><<<1024, 256, 0, stream>>>(
      h0, nullptr, nullptr, w2b, scA, shA, hb, partials, 131072);
  reduce2_kernel<<<64, 256, 0, stream>>>(partials, g2, b2, scBc, shBc, 1024, 64, 1.f / 131072.f);
  apply_kernel<<<4096, 256, 0, stream>>>(hb, fb, scBc, shBc, 1048576, 63);

  fps_kernel<4096, 256><<<32, 256, 0, stream>>>(xyz, fps1, 512);
  gather_kernel<512, 4096, 64><<<16384, 64, 0, stream>>>(fps1, xyz, fb, xyzc1, fcen1);
  knn_kernel<4096, 512><<<16384, 256, 0, stream>>>(xyz, xyzc1, knn1);

  gemm_kernel<128, 128, true, false, 4096, 512><<<4096, 256, 0, stream>>>(
      fb, fcen1, knn1, W1pp, nullptr, nullptr, hbuf, partials, 524288);
  reduce2_kernel<<<128, 256, 0, stream>>>(partials, s1g1, s1b1, sc1a, sh1a, 4096, 128, 1.f / 524288.f);
  gemm_kernel<128, 128, false, true, 1, 1><<<4096, 256, 0, stream>>>(
      hbuf, nullptr, nullptr, s1w2b, sc1a, sh1a, hbuf, partials, 524288);
  reduce2_kernel<<<128, 256, 0, stream>>>(partials, s1g2, s1b2, sc1b, sh1b, 4096, 128, 1.f / 524288.f);
  maxpool_f1_kernel<<<16384, 128, 0, stream>>>(hbuf, sc1b, sh1b, f1);

  fps_kernel<512, 256><<<32, 256, 0, stream>>>(xyzc1, fps2, 256);
  gather_kernel<256, 512, 128><<<8192, 128, 0, stream>>>(fps2, xyzc1, f1, xyzc2, fcen2);
  knn_kernel<512, 256><<<8192, 256, 0, stream>>>(xyzc1, xyzc2, knn2);

  gemm_kernel<256, 256, true, false, 512, 256><<<4096, 256, 0, stream>>>(
      f1, fcen2, knn2, W2pp, nullptr, nullptr, hbuf, partials, 262144);
  reduce2_kernel<<<256, 256, 0, stream>>>(partials, s2g1, s2b1, sc2a, sh2a, 4096, 256, 1.f / 262144.f);
  gemm_kernel<256, 256, false, true, 1, 1><<<4096, 256, 0, stream>>>(
      hbuf, nullptr, nullptr, s2w2b, sc2a, sh2a, hbuf, partials, 262144);
  reduce2_kernel<<<256, 256, 0, stream>>>(partials, s2g2, s2b2, sc2b, sh2b, 4096, 256, 1.f / 262144.f);
  maxpool_out_kernel<<<8192, 256, 0, stream>>>(hbuf, sc2b, sh2b, out);
}

// Round 8
// 1280.807 us; speedup vs baseline: 1.7083x; 1.1384x over previous
//
#include <hip/hip_runtime.h>

// ---------- types & helpers ----------
typedef short short8 __attribute__((ext_vector_type(8)));
typedef _Float16 h8 __attribute__((ext_vector_type(8)));
typedef float f32x4 __attribute__((ext_vector_type(4)));

#define DEVI __device__ __forceinline__

DEVI float h2f(short s) { return (float)__builtin_bit_cast(_Float16, s); }
DEVI short f2h(float f) { return __builtin_bit_cast(short, (_Float16)f); }
DEVI f32x4 mfma16(short8 a, short8 b, f32x4 c) {
  return __builtin_amdgcn_mfma_f32_16x16x32_f16(
      __builtin_bit_cast(h8, a), __builtin_bit_cast(h8, b), c, 0, 0, 0);
}

// ---------- DPP 64-lane reductions (gfx9 pattern), result broadcast ----------
DEVI float wave_max_bcast(float v) {
  const int ID = 0xff800000;  // -inf
  int x = __builtin_bit_cast(int, v);
#define STEPM(ctrl)                                                     \
  {                                                                     \
    int t = __builtin_amdgcn_update_dpp(ID, x, ctrl, 0xf, 0xf, false);  \
    x = __builtin_bit_cast(int, fmaxf(__builtin_bit_cast(float, x),     \
                                      __builtin_bit_cast(float, t)));   \
  }
  STEPM(0x111) STEPM(0x112) STEPM(0x114) STEPM(0x118) STEPM(0x142) STEPM(0x143)
#undef STEPM
  return __builtin_bit_cast(float, __builtin_amdgcn_readlane(x, 63));
}
DEVI float wave_min_bcast_f(float v) {
  const int ID = 0x7f800000;  // +inf
  int x = __builtin_bit_cast(int, v);
#define STEPN(ctrl)                                                     \
  {                                                                     \
    int t = __builtin_amdgcn_update_dpp(ID, x, ctrl, 0xf, 0xf, false);  \
    x = __builtin_bit_cast(int, fminf(__builtin_bit_cast(float, x),     \
                                      __builtin_bit_cast(float, t)));   \
  }
  STEPN(0x111) STEPN(0x112) STEPN(0x114) STEPN(0x118) STEPN(0x142) STEPN(0x143)
#undef STEPN
  return __builtin_bit_cast(float, __builtin_amdgcn_readlane(x, 63));
}
DEVI unsigned wave_min_bcast_u(unsigned v) {
  const int ID = (int)0xffffffff;
  int x = (int)v;
#define STEPU(ctrl)                                                     \
  {                                                                     \
    int t = __builtin_amdgcn_update_dpp(ID, x, ctrl, 0xf, 0xf, false);  \
    x = (int)((unsigned)x < (unsigned)t ? (unsigned)x : (unsigned)t);   \
  }
  STEPU(0x111) STEPU(0x112) STEPU(0x114) STEPU(0x118) STEPU(0x142) STEPU(0x143)
#undef STEPU
  return (unsigned)__builtin_amdgcn_readlane(x, 63);
}

// ---------- weight prep: f16 casts + folded W'' = [w1a | w1b - w1a] ----------
__global__ __launch_bounds__(256) void prep_kernel(
    const float* __restrict__ w2, const float* __restrict__ s1w2,
    const float* __restrict__ s2w2, const float* __restrict__ s1w1,
    const float* __restrict__ s2w1, short* __restrict__ w2b,
    short* __restrict__ s1w2b, short* __restrict__ s2w2b,
    short* __restrict__ W1pp, short* __restrict__ W2pp) {
  int i = blockIdx.x * 256 + threadIdx.x;
  if (i < 4096) {
    w2b[i] = f2h(w2[i]);
  } else if (i < 20480) {
    int j = i - 4096; s1w2b[j] = f2h(s1w2[j]);
  } else if (i < 86016) {
    int j = i - 20480; s2w2b[j] = f2h(s2w2[j]);
  } else if (i < 102400) {
    int j = i - 86016; int c = j & 127;
    float v = s1w1[j]; if (c >= 64) v -= s1w1[j - 64];
    W1pp[j] = f2h(v);
  } else if (i < 167936) {
    int j = i - 102400; int c = j & 255;
    float v = s2w1[j]; if (c >= 128) v -= s2w1[j - 128];
    W2pp[j] = f2h(v);
  }
}

// ---------- stage A: xyz transpose + h0 = x @ w1^T (K=3, VALU fp32) ----------
__global__ __launch_bounds__(256) void stageA_kernel(
    const float* __restrict__ x, const float* __restrict__ w1,
    float* __restrict__ xyz, short* __restrict__ h0) {
  int i = blockIdx.x * 256 + threadIdx.x;  // b*4096 + n, < 131072
  int b = i >> 12, n = i & 4095;
  const float* xb = x + ((size_t)b * 3 << 12) + n;
  float x0 = xb[0], x1 = xb[4096], x2 = xb[8192];
  float* xp = xyz + (size_t)i * 3;
  xp[0] = x0; xp[1] = x1; xp[2] = x2;
  short* hp = h0 + ((size_t)i << 6);
#pragma unroll
  for (int o8 = 0; o8 < 8; ++o8) {
    short8 t;
#pragma unroll
    for (int j = 0; j < 8; ++j) {
      int o = o8 * 8 + j;
      float h = x0 * w1[o * 3] + x1 * w1[o * 3 + 1] + x2 * w1[o * 3 + 2];
      t[j] = f2h(h);
    }
    *reinterpret_cast<short8*>(hp + o8 * 8) = t;
  }
}

// ---------- channel stats for a [M][64] f16 tensor -> transposed partials ----------
__global__ __launch_bounds__(256) void stats64_kernel(
    const short* __restrict__ h, float* __restrict__ partials, int M) {
  __shared__ float l0[256], l1[256];
  const int tid = threadIdx.x;
  const int c = tid & 63, g = tid >> 6;
  float s0 = 0.f, s1 = 0.f;
  for (int m = blockIdx.x * 4 + g; m < M; m += gridDim.x * 4) {
    float v = h2f(h[(size_t)m * 64 + c]);
    s0 += v; s1 += v * v;
  }
  l0[tid] = s0; l1[tid] = s1;
  __syncthreads();
  if (g == 0) {
    for (int w = 1; w < 4; ++w) { s0 += l0[c + w * 64]; s1 += l1[c + w * 64]; }
    partials[(size_t)c * gridDim.x + blockIdx.x] = s0;
    partials[(size_t)(64 + c) * gridDim.x + blockIdx.x] = s1;
  }
}

// ---------- fused reduce + BN finalize: block c -> scale[c], shift[c] ----------
__global__ __launch_bounds__(256) void reduce2_kernel(
    const float* __restrict__ partials, const float* __restrict__ gamma,
    const float* __restrict__ beta, float* __restrict__ scale,
    float* __restrict__ shift, int NB, int C, float invM) {
  __shared__ float l0[4], l1[4];
  const int c = blockIdx.x, tid = threadIdx.x;
  const float* p0 = partials + (size_t)c * NB;
  const float* p1 = partials + (size_t)(C + c) * NB;
  float s0 = 0.f, s1 = 0.f;
  for (int i = tid; i < NB; i += 256) { s0 += p0[i]; s1 += p1[i]; }
#pragma unroll
  for (int off = 1; off < 64; off <<= 1) {
    s0 += __shfl_xor(s0, off);
    s1 += __shfl_xor(s1, off);
  }
  if ((tid & 63) == 0) { l0[tid >> 6] = s0; l1[tid >> 6] = s1; }
  __syncthreads();
  if (tid == 0) {
    s0 = l0[0] + l0[1] + l0[2] + l0[3];
    s1 = l1[0] + l1[1] + l1[2] + l1[3];
    float mean = s0 * invM;
    float var = fmaxf(s1 * invM - mean * mean, 0.f);
    float sc = gamma[c] / sqrtf(var + 1e-5f);
    scale[c] = sc;
    shift[c] = beta[c] - mean * sc;
  }
}

// ---------- bodies for fused kernels ----------

// BN+ReLU apply, 8 f16/thread; grid portion exactly 4096 blocks (C=64 tensors)
DEVI void apply_body(int bid, int tid, const short* __restrict__ h,
                     short* __restrict__ f, const float* __restrict__ scale,
                     const float* __restrict__ shift) {
  size_t i = ((size_t)bid * 256 + tid) * 8;
  int c0 = (int)(i & 63);
  short8 v = *reinterpret_cast<const short8*>(h + i);
  short8 o;
#pragma unroll
  for (int j = 0; j < 8; ++j) {
    float y = h2f(v[j]) * scale[c0 + j] + shift[c0 + j];
    o[j] = f2h(fmaxf(y, 0.f));
  }
  *reinterpret_cast<short8*>(f + i) = o;
}

// FPS (v4 lean structure) + progressive xyzc emission (selected coords).
// Exact numpy semantics: unfused fp32 distances, argmax tie -> smallest index.
template <int NPTS, int T>
DEVI void fps_body(char* smemraw, int bid, int tid, const float* __restrict__ xyz,
                   int* __restrict__ out, float* __restrict__ xyzc, int nsel) {
  constexpr int PT = NPTS / T;
  constexpr int NW = T / 64;
  float* sx = (float*)smemraw;
  float* sy = sx + NPTS;
  float* sz = sy + NPTS;
  float* wv = sz + NPTS;                    // [2][NW]
  unsigned* wi = (unsigned*)(wv + 2 * NW);  // [2][NW]
  const int lane = tid & 63, wave = tid >> 6;
  const float* base = xyz + (size_t)bid * NPTS * 3;
  float px[PT], py[PT], pz[PT], dmin[PT];
#pragma unroll
  for (int j = 0; j < PT; ++j) {
    int n = j * T + tid;
    px[j] = base[n * 3]; py[j] = base[n * 3 + 1]; pz[j] = base[n * 3 + 2];
    sx[n] = px[j]; sy[n] = py[j]; sz[n] = pz[j];
    dmin[j] = 1e10f;
  }
  __syncthreads();
  int far = 0;
  float cx = sx[0], cy = sy[0], cz = sz[0];
  for (int it = 0; it < nsel; ++it) {
    if (tid == 0) {
      out[bid * nsel + it] = far;
      if (xyzc) {
        float* xc = xyzc + ((size_t)bid * nsel + it) * 3;
        xc[0] = cx; xc[1] = cy; xc[2] = cz;
      }
    }
    float bv = -1.f;
#pragma unroll
    for (int j = 0; j < PT; ++j) {
      float dx = __fsub_rn(px[j], cx), dy = __fsub_rn(py[j], cy), dz = __fsub_rn(pz[j], cz);
      float d = __fadd_rn(__fadd_rn(__fmul_rn(dx, dx), __fmul_rn(dy, dy)), __fmul_rn(dz, dz));
      float dm = fminf(dmin[j], d);
      dmin[j] = dm;
      bv = fmaxf(bv, dm);
    }
    float wmv = wave_max_bcast(bv);
    unsigned ci = 0xffffffffu;  // rescan, descending j -> smallest index kept
#pragma unroll
    for (int j = PT - 1; j >= 0; --j)
      if (dmin[j] == wmv) ci = (unsigned)(j * T + tid);
    unsigned wmi = wave_min_bcast_u(ci);
    const int bsel = it & 1;
    if (lane == 0) { wv[bsel * NW + wave] = wmv; wi[bsel * NW + wave] = wmi; }
    __syncthreads();
    const int e = lane & (NW - 1);
    float v = wv[bsel * NW + e];
    unsigned si = wi[bsel * NW + e];
#define CMB(ctrl)                                                                        \
  {                                                                                      \
    float v2 = __builtin_bit_cast(                                                       \
        float, __builtin_amdgcn_update_dpp(0, __builtin_bit_cast(int, v), ctrl, 0xf, 0xf, true)); \
    unsigned i2 = (unsigned)__builtin_amdgcn_update_dpp(0, (int)si, ctrl, 0xf, 0xf, true);\
    bool bt = (v2 > v) || (v2 == v && i2 < si);                                          \
    v = bt ? v2 : v; si = bt ? i2 : si;                                                  \
  }
    if constexpr (NW >= 2) CMB(0x121)   // row_ror:1
    if constexpr (NW >= 4) CMB(0x122)   // row_ror:2
    if constexpr (NW >= 8) CMB(0x124)   // row_ror:4
#undef CMB
    far = (int)si;
    cx = sx[far]; cy = sy[far]; cz = sz[far];  // broadcast LDS read, once/iter
  }
}

// kNN: centers read via fps index (no gathered ctr buffer needed)
template <int NPTS, int S>
DEVI void knn_body(char* smemraw, int bid, int tid, const float* __restrict__ pts,
                   const int* __restrict__ fpsidx, int* __restrict__ knn) {
  constexpr int PT = NPTS / 256;
  float* wv = (float*)smemraw;          // [2][4]
  unsigned* wi = (unsigned*)(wv + 8);   // [2][4]
  const int lane = tid & 63, wave = tid >> 6;
  const int b = bid / S;
  const int cidx = fpsidx[bid];
  const float* cp = pts + ((size_t)b * NPTS + cidx) * 3;
  const float qx = cp[0], qy = cp[1], qz = cp[2];
  const float qq = __fadd_rn(__fadd_rn(__fmul_rn(qx, qx), __fmul_rn(qy, qy)), __fmul_rn(qz, qz));
  const float* base = pts + (size_t)b * NPTS * 3;
  float d[PT];
#pragma unroll
  for (int j = 0; j < PT; ++j) {
    int n = j * 256 + tid;
    float x = base[n * 3], y = base[n * 3 + 1], z = base[n * 3 + 2];
    float pp = __fadd_rn(__fadd_rn(__fmul_rn(x, x), __fmul_rn(y, y)), __fmul_rn(z, z));
    float dot = __fadd_rn(__fadd_rn(__fmul_rn(qx, x), __fmul_rn(qy, y)), __fmul_rn(qz, z));
    d[j] = __fsub_rn(__fadd_rn(qq, pp), __fmul_rn(2.f, dot));
  }
  unsigned sel = 0;
  float bv = 3.4e38f; unsigned bi = 0x7fffffffu;
#pragma unroll
  for (int j = 0; j < PT; ++j)
    if (d[j] < bv) { bv = d[j]; bi = (unsigned)(j * 256 + tid); }
  for (int k = 0; k < 32; ++k) {
    float wmv = wave_min_bcast_f(bv);
    unsigned ci = (bv == wmv) ? bi : 0x7fffffffu;
    unsigned wmi = wave_min_bcast_u(ci);
    const int ksel = k & 1;
    if (lane == 0) { wv[ksel * 4 + wave] = wmv; wi[ksel * 4 + wave] = wmi; }
    __syncthreads();
    float gv = wv[ksel * 4]; unsigned gi = wi[ksel * 4];
#pragma unroll
    for (int w = 1; w < 4; ++w) {
      float ov = wv[ksel * 4 + w]; unsigned oi = wi[ksel * 4 + w];
      bool t = (ov < gv) || (ov == gv && oi < gi);
      gv = t ? ov : gv; gi = t ? oi : gi;
    }
    if (tid == 0) knn[(size_t)bid * 32 + k] = (int)gi;
    if ((gi & 255u) == (unsigned)tid) {  // winner rescans its candidates
      sel |= 1u << (gi >> 8);
      bv = 3.4e38f; bi = 0x7fffffffu;
#pragma unroll
      for (int j = 0; j < PT; ++j)
        if (!((sel >> j) & 1u) && d[j] < bv) { bv = d[j]; bi = (unsigned)(j * 256 + tid); }
    }
  }
}

// MFMA GEMM with chunked W-staging (few barriers) + BN stat partials.
// GATHER: A-row m: half0 = T[b, knn[m], :], half1 = T[b, fps[center(m)], :]
// BNA: BN+ReLU applied to A on load.
template <int KD, int ND, bool GATHER, bool BNA, int NPTS, int S>
DEVI void gemm_body(char* smemraw, int bid, int tid, int gemmBlocks,
                    const short* A, const int* KNNp, const int* FPSp,
                    const short* __restrict__ W, const float* __restrict__ bnscale,
                    const float* __restrict__ bnshift, short* Hout,
                    float* __restrict__ partials) {
  constexpr int C = KD / 2;
  constexpr int NT = (ND > 128) ? 8 : ND / 16;
  constexpr int BR = (ND > 128) ? 64 : 128;
  constexpr int KC = (ND >= 256) ? 64 : KD;       // staging chunk k-width
  constexpr int LOG2KC = (KC == 64) ? 6 : 7;
  constexpr int NCH = KD / KC;
  constexpr int KTC = KC / 32;
  constexpr int LROW = KC + 8;                    // +16B pad -> 2-way alias (free)
  short* lb = (short*)smemraw;                    // [ND][LROW]
  float* lstats = (float*)(smemraw + ND * LROW * 2);
  const int wave = tid >> 6, lane = tid & 63;
  const int rowOff = (ND > 128) ? (wave >> 1) * 32 : wave * 32;
  const int colOff = (ND > 128) ? (wave & 1) * 128 : 0;
  const int mBase = bid * BR + rowOff;
  for (int i = tid; i < 2 * ND; i += 256) lstats[i] = 0.f;

  const short* aptr[2][2];
#pragma unroll
  for (int rg = 0; rg < 2; ++rg) {
    int m = mBase + rg * 16 + (lane & 15);
    if constexpr (GATHER) {
      int idx = KNNp[m];
      int bb = m / (S * 32);
      int s = (m - bb * (S * 32)) >> 5;
      int fidx = FPSp[bb * S + s];
      aptr[rg][0] = A + ((size_t)bb * NPTS + idx) * C;
      aptr[rg][1] = A + ((size_t)bb * NPTS + fidx) * C;
    } else {
      aptr[rg][0] = A + (size_t)m * KD;
      aptr[rg][1] = A + (size_t)m * KD + C;
    }
  }
  const int koLane = (lane >> 4) * 8;
  f32x4 acc[2][NT];
#pragma unroll
  for (int rg = 0; rg < 2; ++rg)
#pragma unroll
    for (int nt = 0; nt < NT; ++nt) acc[rg][nt] = (f32x4){0.f, 0.f, 0.f, 0.f};

#pragma unroll
  for (int ch = 0; ch < NCH; ++ch) {
    __syncthreads();
    constexpr int SIT = (ND * KC) / 2048;
#pragma unroll
    for (int i = 0; i < SIT; ++i) {
      int e = i * 2048 + tid * 8;
      int n = e >> LOG2KC, kk = e & (KC - 1);
      short8 v = *reinterpret_cast<const short8*>(W + (size_t)n * KD + ch * KC + kk);
      *reinterpret_cast<short8*>(&lb[n * LROW + kk]) = v;
    }
    __syncthreads();
#pragma unroll
    for (int ktc = 0; ktc < KTC; ++ktc) {
      const int kt = ch * KTC + ktc;
      const int half = (kt * 32 >= C) ? 1 : 0;
      const int ko = kt * 32 + koLane;
      const int koh = ko - half * C;
      short8 afrag[2];
#pragma unroll
      for (int rg = 0; rg < 2; ++rg) {
        short8 a = *reinterpret_cast<const short8*>(aptr[rg][half] + koh);
        if constexpr (BNA) {
          const float* scp = bnscale + ko;
          const float* shp = bnshift + ko;
#pragma unroll
          for (int j = 0; j < 8; ++j) {
            float v = h2f(a[j]);
            v = fmaxf(v * scp[j] + shp[j], 0.f);
            a[j] = f2h(v);
          }
        }
        afrag[rg] = a;
      }
#pragma unroll
      for (int nt = 0; nt < NT; ++nt) {
        short8 bfr = *reinterpret_cast<const short8*>(
            &lb[(colOff + nt * 16 + (lane & 15)) * LROW + ktc * 32 + koLane]);
        acc[0][nt] = mfma16(afrag[0], bfr, acc[0][nt]);
        acc[1][nt] = mfma16(afrag[1], bfr, acc[1][nt]);
      }
    }
  }
  __syncthreads();  // all A-reads done before in-place stores

  // per-channel sum / sumsq partials
#pragma unroll
  for (int nt = 0; nt < NT; ++nt) {
    float s0 = 0.f, s1 = 0.f;
#pragma unroll
    for (int rg = 0; rg < 2; ++rg)
#pragma unroll
      for (int i = 0; i < 4; ++i) {
        float v = acc[rg][nt][i];
        s0 += v; s1 += v * v;
      }
    s0 += __shfl_xor(s0, 16); s0 += __shfl_xor(s0, 32);
    s1 += __shfl_xor(s1, 16); s1 += __shfl_xor(s1, 32);
    if (lane < 16) {
      atomicAdd(&lstats[colOff + nt * 16 + lane], s0);
      atomicAdd(&lstats[ND + colOff + nt * 16 + lane], s1);
    }
  }
  // store output (C/D layout: row = 4*(lane>>4)+i, col = lane&15)
#pragma unroll
  for (int rg = 0; rg < 2; ++rg)
#pragma unroll
    for (int nt = 0; nt < NT; ++nt)
#pragma unroll
      for (int i = 0; i < 4; ++i) {
        int m2 = mBase + rg * 16 + (lane >> 4) * 4 + i;
        int n = colOff + nt * 16 + (lane & 15);
        Hout[(size_t)m2 * ND + n] = f2h(acc[rg][nt][i]);
      }
  __syncthreads();
  for (int i = tid; i < 2 * ND; i += 256)
    partials[(size_t)i * gemmBlocks + bid] = lstats[i];
}

// ---------- fused / wrapper kernels ----------

// fps blocks FIRST (dispatch immediately), gemm blocks after
template <int KD, int ND, bool BNA, int FN, int FT>
__global__ __launch_bounds__(256, 1) void gemm_fps_kernel(
    int fpsBlocks, const short* A, const short* W, const float* bnscale,
    const float* bnshift, short* Hout, float* partials,
    const float* fxyz, int* fout, float* fxyzc, int fnsel) {
  extern __shared__ char smem[];
  if ((int)blockIdx.x < fpsBlocks)
    fps_body<FN, FT>(smem, blockIdx.x, threadIdx.x, fxyz, fout, fxyzc, fnsel);
  else
    gemm_body<KD, ND, false, BNA, 1, 1>(smem, blockIdx.x - fpsBlocks, threadIdx.x,
                                        gridDim.x - fpsBlocks, A, nullptr, nullptr,
                                        W, bnscale, bnshift, Hout, partials);
}

template <int KD, int ND, bool GATHER, bool BNA, int NPTS, int S>
__global__ __launch_bounds__(256, 2) void gemm_kernel(
    const short* A, const int* KNNp, const int* FPSp, const short* W,
    const float* bnscale, const float* bnshift, short* Hout, float* partials) {
  extern __shared__ char smem[];
  gemm_body<KD, ND, GATHER, BNA, NPTS, S>(smem, blockIdx.x, threadIdx.x, gridDim.x,
                                          A, KNNp, FPSp, W, bnscale, bnshift, Hout,
                                          partials);
}

// knn blocks first, then apply blocks
template <int NPTS, int S>
__global__ __launch_bounds__(256, 1) void knn_apply_kernel(
    int knnBlocks, const float* pts, const int* fpsidx, int* knn,
    const short* ah, short* af, const float* ascale, const float* ashift) {
  extern __shared__ char smem[];
  if ((int)blockIdx.x < knnBlocks)
    knn_body<NPTS, S>(smem, blockIdx.x, threadIdx.x, pts, fpsidx, knn);
  else
    apply_body(blockIdx.x - knnBlocks, threadIdx.x, ah, af, ascale, ashift);
}

// knn blocks first, then maxpool-f1 blocks (2 rows per 256-thr block)
template <int NPTS, int S>
__global__ __launch_bounds__(256, 1) void maxpool_knn_kernel(
    int knnBlocks, const float* pts, const int* fpsidx, int* knn,
    const short* h, const float* scale, const float* shift, short* f1) {
  extern __shared__ char smem[];
  if ((int)blockIdx.x < knnBlocks) {
    knn_body<NPTS, S>(smem, blockIdx.x, threadIdx.x, pts, fpsidx, knn);
  } else {
    const int bs = (blockIdx.x - knnBlocks) * 2 + (threadIdx.x >> 7);
    const int c = threadIdx.x & 127;
    const float sc = scale[c], sh = shift[c];
    float m = 0.f;  // relu outputs >= 0
    for (int k = 0; k < 32; ++k) {
      float v = h2f(h[((size_t)bs * 32 + k) * 128 + c]);
      m = fmaxf(m, fmaxf(v * sc + sh, 0.f));
    }
    f1[(size_t)bs * 128 + c] = f2h(m);
  }
}

// ---------- final: max over K with BN+ReLU, transposed fp32 out [B][C][S] ----------
__global__ __launch_bounds__(256) void maxpool_out_kernel(
    const short* __restrict__ h, const float* __restrict__ scale,
    const float* __restrict__ shift, float* __restrict__ out) {
  const int bs = blockIdx.x, c = threadIdx.x;
  const int b = bs >> 8, s = bs & 255;
  const float sc = scale[c], sh = shift[c];
  float m = 0.f;
  for (int k = 0; k < 32; ++k) {
    float v = h2f(h[((size_t)bs * 32 + k) * 256 + c]);
    m = fmaxf(m, fmaxf(v * sc + sh, 0.f));
  }
  out[((size_t)b << 16) + ((size_t)c << 8) + s] = m;
}

// ---------- launch ----------
extern "C" void kernel_launch(void* const* d_in, const int* in_sizes, int n_in,
                              void* d_out, int out_size, void* d_ws, size_t ws_size,
                              hipStream_t stream) {
  (void)in_sizes; (void)n_in; (void)out_size; (void)ws_size;
  const float* x    = (const float*)d_in[0];
  const float* w1   = (const float*)d_in[1];
  const float* g1   = (const float*)d_in[2];
  const float* b1   = (const float*)d_in[3];
  const float* w2   = (const float*)d_in[4];
  const float* g2   = (const float*)d_in[5];
  const float* b2   = (const float*)d_in[6];
  const float* s1w1 = (const float*)d_in[7];
  const float* s1g1 = (const float*)d_in[8];
  const float* s1b1 = (const float*)d_in[9];
  const float* s1w2 = (const float*)d_in[10];
  const float* s1g2 = (const float*)d_in[11];
  const float* s1b2 = (const float*)d_in[12];
  const float* s2w1 = (const float*)d_in[13];
  const float* s2g1 = (const float*)d_in[14];
  const float* s2b1 = (const float*)d_in[15];
  const float* s2w2 = (const float*)d_in[16];
  const float* s2g2 = (const float*)d_in[17];
  const float* s2b2 = (const float*)d_in[18];
  float* out = (float*)d_out;

  char* ws = (char*)d_ws;
  size_t off = 0;
  auto alloc = [&](size_t bytes) -> char* {
    size_t p = (off + 255) & ~(size_t)255;
    off = p + bytes;
    return ws + p;
  };

  float* xyz      = (float*)alloc(32ull * 4096 * 3 * 4);
  short* h0       = (short*)alloc(32ull * 4096 * 64 * 2);
  short* hb       = (short*)alloc(32ull * 4096 * 64 * 2);
  short* fb       = (short*)alloc(32ull * 4096 * 64 * 2);
  int*   fps1     = (int*)alloc(32ull * 512 * 4);
  float* xyzc1    = (float*)alloc(32ull * 512 * 3 * 4);
  int*   knn1     = (int*)alloc(32ull * 512 * 32 * 4);
  short* f1       = (short*)alloc(32ull * 512 * 128 * 2);
  int*   fps2     = (int*)alloc(32ull * 256 * 4);
  int*   knn2     = (int*)alloc(32ull * 256 * 32 * 4);
  short* hbuf     = (short*)alloc(134217728ull);          // shared SG1/SG2 h buffer
  float* partials = (float*)alloc(2ull * 256 * 4096 * 4); // 8 MB
  float* scA  = (float*)alloc(64 * 4);  float* shA  = (float*)alloc(64 * 4);
  float* scBc = (float*)alloc(64 * 4);  float* shBc = (float*)alloc(64 * 4);
  float* sc1a = (float*)alloc(128 * 4); float* sh1a = (float*)alloc(128 * 4);
  float* sc1b = (float*)alloc(128 * 4); float* sh1b = (float*)alloc(128 * 4);
  float* sc2a = (float*)alloc(256 * 4); float* sh2a = (float*)alloc(256 * 4);
  float* sc2b = (float*)alloc(256 * 4); float* sh2b = (float*)alloc(256 * 4);
  short* w2b   = (short*)alloc(4096 * 2);
  short* s1w2b = (short*)alloc(16384 * 2);
  short* s2w2b = (short*)alloc(65536 * 2);
  short* W1pp  = (short*)alloc(16384 * 2);
  short* W2pp  = (short*)alloc(65536 * 2);

  prep_kernel<<<656, 256, 0, stream>>>(w2, s1w2, s2w2, s1w1, s2w1, w2b, s1w2b, s2w2b, W1pp, W2pp);
  stageA_kernel<<<512, 256, 0, stream>>>(x, w1, xyz, h0);
  stats64_kernel<<<256, 256, 0, stream>>>(h0, partials, 131072);
  reduce2_kernel<<<64, 256, 0, stream>>>(partials, g1, b1, scA, shA, 256, 64, 1.f / 131072.f);

  // fps1 (32 blocks, ~350us) || MLP layer-2 gemm (1024 blocks, hidden)
  gemm_fps_kernel<64, 64, true, 4096, 256><<<1056, 256, 49216, stream>>>(
      32, h0, w2b, scA, shA, hb, partials, xyz, fps1, xyzc1, 512);
  reduce2_kernel<<<64, 256, 0, stream>>>(partials, g2, b2, scBc, shBc, 1024, 64, 1.f / 131072.f);

  // knn1 (16384 blocks) || apply BN+ReLU -> fb (4096 blocks, hidden)
  knn_apply_kernel<4096, 512><<<20480, 256, 64, stream>>>(
      16384, xyz, fps1, knn1, hb, fb, scBc, shBc);

  gemm_kernel<128, 128, true, false, 4096, 512><<<4096, 256, 35840, stream>>>(
      fb, knn1, fps1, W1pp, nullptr, nullptr, hbuf, partials);
  reduce2_kernel<<<128, 256, 0, stream>>>(partials, s1g1, s1b1, sc1a, sh1a, 4096, 128, 1.f / 524288.f);

  // fps2 (32 blocks) || SG1 gemm2 in-place BNA (4096 blocks)
  gemm_fps_kernel<128, 128, true, 512, 256><<<4128, 256, 35840, stream>>>(
      32, hbuf, s1w2b, sc1a, sh1a, hbuf, partials, xyzc1, fps2, nullptr, 256);
  reduce2_kernel<<<128, 256, 0, stream>>>(partials, s1g2, s1b2, sc1b, sh1b, 4096, 128, 1.f / 524288.f);

  // knn2 (8192 blocks) || maxpool_f1 (8192 blocks, 2 rows each)
  maxpool_knn_kernel<512, 256><<<16384, 256, 64, stream>>>(
      8192, xyzc1, fps2, knn2, hbuf, sc1b, sh1b, f1);

  gemm_kernel<256, 256, true, false, 512, 256><<<4096, 256, 38912, stream>>>(
      f1, knn2, fps2, W2pp, nullptr, nullptr, hbuf, partials);
  reduce2_kernel<<<256, 256, 0, stream>>>(partials, s2g1, s2b1, sc2a, sh2a, 4096, 256, 1.f / 262144.f);
  gemm_kernel<256, 256, false, true, 1, 1><<<4096, 256, 38912, stream>>>(
      hbuf, nullptr, nullptr, s2w2b, sc2a, sh2a, hbuf, partials);
  reduce2_kernel<<<256, 256, 0, stream>>>(partials, s2g2, s2b2, sc2b, sh2b, 4096, 256, 1.f / 262144.f);
  maxpool_out_kernel<<<8192, 256, 0, stream>>>(hbuf, sc2b, sh2b, out);
}

// Round 9
// 1216.420 us; speedup vs baseline: 1.7987x; 1.0529x over previous
//
#include <hip/hip_runtime.h>

// ---------- types & helpers ----------
typedef short short8 __attribute__((ext_vector_type(8)));
typedef _Float16 h8 __attribute__((ext_vector_type(8)));
typedef float f32x4 __attribute__((ext_vector_type(4)));

#define DEVI __device__ __forceinline__

DEVI float h2f(short s) { return (float)__builtin_bit_cast(_Float16, s); }
DEVI short f2h(float f) { return __builtin_bit_cast(short, (_Float16)f); }
DEVI f32x4 mfma16(short8 a, short8 b, f32x4 c) {
  return __builtin_amdgcn_mfma_f32_16x16x32_f16(
      __builtin_bit_cast(h8, a), __builtin_bit_cast(h8, b), c, 0, 0, 0);
}

// ---------- DPP 64-lane reductions (gfx9 pattern), result broadcast ----------
DEVI float wave_max_bcast(float v) {
  const int ID = 0xff800000;  // -inf
  int x = __builtin_bit_cast(int, v);
#define STEPM(ctrl)                                                     \
  {                                                                     \
    int t = __builtin_amdgcn_update_dpp(ID, x, ctrl, 0xf, 0xf, false);  \
    x = __builtin_bit_cast(int, fmaxf(__builtin_bit_cast(float, x),     \
                                      __builtin_bit_cast(float, t)));   \
  }
  STEPM(0x111) STEPM(0x112) STEPM(0x114) STEPM(0x118) STEPM(0x142) STEPM(0x143)
#undef STEPM
  return __builtin_bit_cast(float, __builtin_amdgcn_readlane(x, 63));
}
DEVI float wave_min_bcast_f(float v) {
  const int ID = 0x7f800000;  // +inf
  int x = __builtin_bit_cast(int, v);
#define STEPN(ctrl)                                                     \
  {                                                                     \
    int t = __builtin_amdgcn_update_dpp(ID, x, ctrl, 0xf, 0xf, false);  \
    x = __builtin_bit_cast(int, fminf(__builtin_bit_cast(float, x),     \
                                      __builtin_bit_cast(float, t)));   \
  }
  STEPN(0x111) STEPN(0x112) STEPN(0x114) STEPN(0x118) STEPN(0x142) STEPN(0x143)
#undef STEPN
  return __builtin_bit_cast(float, __builtin_amdgcn_readlane(x, 63));
}
DEVI unsigned wave_min_bcast_u(unsigned v) {
  const int ID = (int)0xffffffff;
  int x = (int)v;
#define STEPU(ctrl)                                                     \
  {                                                                     \
    int t = __builtin_amdgcn_update_dpp(ID, x, ctrl, 0xf, 0xf, false);  \
    x = (int)((unsigned)x < (unsigned)t ? (unsigned)x : (unsigned)t);   \
  }
  STEPU(0x111) STEPU(0x112) STEPU(0x114) STEPU(0x118) STEPU(0x142) STEPU(0x143)
#undef STEPU
  return (unsigned)__builtin_amdgcn_readlane(x, 63);
}

// ---------- weight prep: f16 casts + folded W'' = [w1a | w1b - w1a] ----------
__global__ __launch_bounds__(256) void prep_kernel(
    const float* __restrict__ w2, const float* __restrict__ s1w2,
    const float* __restrict__ s2w2, const float* __restrict__ s1w1,
    const float* __restrict__ s2w1, short* __restrict__ w2b,
    short* __restrict__ s1w2b, short* __restrict__ s2w2b,
    short* __restrict__ W1pp, short* __restrict__ W2pp) {
  int i = blockIdx.x * 256 + threadIdx.x;
  if (i < 4096) {
    w2b[i] = f2h(w2[i]);
  } else if (i < 20480) {
    int j = i - 4096; s1w2b[j] = f2h(s1w2[j]);
  } else if (i < 86016) {
    int j = i - 20480; s2w2b[j] = f2h(s2w2[j]);
  } else if (i < 102400) {
    int j = i - 86016; int c = j & 127;
    float v = s1w1[j]; if (c >= 64) v -= s1w1[j - 64];
    W1pp[j] = f2h(v);
  } else if (i < 167936) {
    int j = i - 102400; int c = j & 255;
    float v = s2w1[j]; if (c >= 128) v -= s2w1[j - 128];
    W2pp[j] = f2h(v);
  }
}

// ---------- stage A: xyz transpose + h0 = x @ w1^T (K=3, VALU fp32) ----------
__global__ __launch_bounds__(256) void stageA_kernel(
    const float* __restrict__ x, const float* __restrict__ w1,
    float* __restrict__ xyz, short* __restrict__ h0) {
  int i = blockIdx.x * 256 + threadIdx.x;  // b*4096 + n, < 131072
  int b = i >> 12, n = i & 4095;
  const float* xb = x + ((size_t)b * 3 << 12) + n;
  float x0 = xb[0], x1 = xb[4096], x2 = xb[8192];
  float* xp = xyz + (size_t)i * 3;
  xp[0] = x0; xp[1] = x1; xp[2] = x2;
  short* hp = h0 + ((size_t)i << 6);
#pragma unroll
  for (int o8 = 0; o8 < 8; ++o8) {
    short8 t;
#pragma unroll
    for (int j = 0; j < 8; ++j) {
      int o = o8 * 8 + j;
      float h = x0 * w1[o * 3] + x1 * w1[o * 3 + 1] + x2 * w1[o * 3 + 2];
      t[j] = f2h(h);
    }
    *reinterpret_cast<short8*>(hp + o8 * 8) = t;
  }
}

// ---------- companion bodies ----------

DEVI void stats64_body(int bid, int nb, int tid, const short* __restrict__ h,
                       float* __restrict__ partials, int M) {
  __shared__ float l0[256], l1[256];
  const int c = tid & 63, g = tid >> 6;
  float s0 = 0.f, s1 = 0.f;
  for (int m = bid * 4 + g; m < M; m += nb * 4) {
    float v = h2f(h[(size_t)m * 64 + c]);
    s0 += v; s1 += v * v;
  }
  l0[tid] = s0; l1[tid] = s1;
  __syncthreads();
  if (g == 0) {
    for (int w = 1; w < 4; ++w) { s0 += l0[c + w * 64]; s1 += l1[c + w * 64]; }
    partials[(size_t)c * nb + bid] = s0;
    partials[(size_t)(64 + c) * nb + bid] = s1;
  }
}

DEVI void reduce2_body(int c, int tid, const float* __restrict__ partials,
                       const float* __restrict__ gamma, const float* __restrict__ beta,
                       float* __restrict__ scale, float* __restrict__ shift,
                       int NB, int C, float invM) {
  __shared__ float l0[4], l1[4];
  const float* p0 = partials + (size_t)c * NB;
  const float* p1 = partials + (size_t)(C + c) * NB;
  float s0 = 0.f, s1 = 0.f;
  for (int i = tid; i < NB; i += 256) { s0 += p0[i]; s1 += p1[i]; }
#pragma unroll
  for (int off = 1; off < 64; off <<= 1) {
    s0 += __shfl_xor(s0, off);
    s1 += __shfl_xor(s1, off);
  }
  if ((tid & 63) == 0) { l0[tid >> 6] = s0; l1[tid >> 6] = s1; }
  __syncthreads();
  if (tid == 0) {
    s0 = l0[0] + l0[1] + l0[2] + l0[3];
    s1 = l1[0] + l1[1] + l1[2] + l1[3];
    float mean = s0 * invM;
    float var = fmaxf(s1 * invM - mean * mean, 0.f);
    float sc = gamma[c] / sqrtf(var + 1e-5f);
    scale[c] = sc;
    shift[c] = beta[c] - mean * sc;
  }
}

__global__ __launch_bounds__(256) void reduce2_kernel(
    const float* __restrict__ partials, const float* __restrict__ gamma,
    const float* __restrict__ beta, float* __restrict__ scale,
    float* __restrict__ shift, int NB, int C, float invM) {
  reduce2_body(blockIdx.x, threadIdx.x, partials, gamma, beta, scale, shift, NB, C, invM);
}

// BN+ReLU apply, 8 f16/thread (C=64 tensors)
DEVI void apply_body(int bid, int tid, const short* __restrict__ h,
                     short* __restrict__ f, const float* __restrict__ scale,
                     const float* __restrict__ shift) {
  size_t i = ((size_t)bid * 256 + tid) * 8;
  int c0 = (int)(i & 63);
  short8 v = *reinterpret_cast<const short8*>(h + i);
  short8 o;
#pragma unroll
  for (int j = 0; j < 8; ++j) {
    float y = h2f(v[j]) * scale[c0 + j] + shift[c0 + j];
    o[j] = f2h(fmaxf(y, 0.f));
  }
  *reinterpret_cast<short8*>(f + i) = o;
}

// ---------- FPS body, segmented: state (dmin, far) round-trips via global ----------
// Exact numpy semantics: unfused fp32 distances, argmax tie -> smallest index.
template <int NPTS, int T>
DEVI void fps_seg_body(char* smemraw, int bid, int tid, const float* __restrict__ xyz,
                       int* __restrict__ out, float* __restrict__ xyzc, int nsel,
                       int it0, int it1, float* __restrict__ dming,
                       int* __restrict__ farg) {
  constexpr int PT = NPTS / T;
  constexpr int NW = T / 64;
  float* sx = (float*)smemraw;
  float* sy = sx + NPTS;
  float* sz = sy + NPTS;
  float* wv = sz + NPTS;                    // [2][NW]
  unsigned* wi = (unsigned*)(wv + 2 * NW);  // [2][NW]
  const int lane = tid & 63, wave = tid >> 6;
  const float* base = xyz + (size_t)bid * NPTS * 3;
  float px[PT], py[PT], pz[PT], dmin[PT];
#pragma unroll
  for (int j = 0; j < PT; ++j) {
    int n = j * T + tid;
    px[j] = base[n * 3]; py[j] = base[n * 3 + 1]; pz[j] = base[n * 3 + 2];
    sx[n] = px[j]; sy[n] = py[j]; sz[n] = pz[j];
  }
  int far;
  if (it0 == 0) {
#pragma unroll
    for (int j = 0; j < PT; ++j) dmin[j] = 1e10f;
    far = 0;
  } else {
#pragma unroll
    for (int j = 0; j < PT; ++j) dmin[j] = dming[(size_t)bid * NPTS + j * T + tid];
    far = farg[bid];
  }
  __syncthreads();
  float cx = sx[far], cy = sy[far], cz = sz[far];
  for (int it = it0; it < it1; ++it) {
    if (tid == 0) {
      out[bid * nsel + it] = far;
      if (xyzc) {
        float* xc = xyzc + ((size_t)bid * nsel + it) * 3;
        xc[0] = cx; xc[1] = cy; xc[2] = cz;
      }
    }
    float bv = -1.f;
#pragma unroll
    for (int j = 0; j < PT; ++j) {
      float dx = __fsub_rn(px[j], cx), dy = __fsub_rn(py[j], cy), dz = __fsub_rn(pz[j], cz);
      float d = __fadd_rn(__fadd_rn(__fmul_rn(dx, dx), __fmul_rn(dy, dy)), __fmul_rn(dz, dz));
      float dm = fminf(dmin[j], d);
      dmin[j] = dm;
      bv = fmaxf(bv, dm);
    }
    float wmv = wave_max_bcast(bv);
    unsigned ci = 0xffffffffu;  // rescan, descending j -> smallest index kept
#pragma unroll
    for (int j = PT - 1; j >= 0; --j)
      if (dmin[j] == wmv) ci = (unsigned)(j * T + tid);
    unsigned wmi = wave_min_bcast_u(ci);
    const int bsel = it & 1;
    if (lane == 0) { wv[bsel * NW + wave] = wmv; wi[bsel * NW + wave] = wmi; }
    __syncthreads();
    const int e = lane & (NW - 1);
    float v = wv[bsel * NW + e];
    unsigned si = wi[bsel * NW + e];
#define CMB(ctrl)                                                                        \
  {                                                                                      \
    float v2 = __builtin_bit_cast(                                                       \
        float, __builtin_amdgcn_update_dpp(0, __builtin_bit_cast(int, v), ctrl, 0xf, 0xf, true)); \
    unsigned i2 = (unsigned)__builtin_amdgcn_update_dpp(0, (int)si, ctrl, 0xf, 0xf, true);\
    bool bt = (v2 > v) || (v2 == v && i2 < si);                                          \
    v = bt ? v2 : v; si = bt ? i2 : si;                                                  \
  }
    if constexpr (NW >= 2) CMB(0x121)   // row_ror:1
    if constexpr (NW >= 4) CMB(0x122)   // row_ror:2
    if constexpr (NW >= 8) CMB(0x124)   // row_ror:4
#undef CMB
    far = (int)si;
    cx = sx[far]; cy = sy[far]; cz = sz[far];  // broadcast LDS read, once/iter
  }
  if (it1 < nsel) {
#pragma unroll
    for (int j = 0; j < PT; ++j) dming[(size_t)bid * NPTS + j * T + tid] = dmin[j];
    if (tid == 0) farg[bid] = far;
  }
}

// kNN: centers read via fps index
template <int NPTS, int S>
DEVI void knn_body(char* smemraw, int bid, int tid, const float* __restrict__ pts,
                   const int* __restrict__ fpsidx, int* __restrict__ knn) {
  constexpr int PT = NPTS / 256;
  float* wv = (float*)smemraw;          // [2][4]
  unsigned* wi = (unsigned*)(wv + 8);   // [2][4]
  const int lane = tid & 63, wave = tid >> 6;
  const int b = bid / S;
  const int cidx = fpsidx[bid];
  const float* cp = pts + ((size_t)b * NPTS + cidx) * 3;
  const float qx = cp[0], qy = cp[1], qz = cp[2];
  const float qq = __fadd_rn(__fadd_rn(__fmul_rn(qx, qx), __fmul_rn(qy, qy)), __fmul_rn(qz, qz));
  const float* base = pts + (size_t)b * NPTS * 3;
  float d[PT];
#pragma unroll
  for (int j = 0; j < PT; ++j) {
    int n = j * 256 + tid;
    float x = base[n * 3], y = base[n * 3 + 1], z = base[n * 3 + 2];
    float pp = __fadd_rn(__fadd_rn(__fmul_rn(x, x), __fmul_rn(y, y)), __fmul_rn(z, z));
    float dot = __fadd_rn(__fadd_rn(__fmul_rn(qx, x), __fmul_rn(qy, y)), __fmul_rn(qz, z));
    d[j] = __fsub_rn(__fadd_rn(qq, pp), __fmul_rn(2.f, dot));
  }
  unsigned sel = 0;
  float bv = 3.4e38f; unsigned bi = 0x7fffffffu;
#pragma unroll
  for (int j = 0; j < PT; ++j)
    if (d[j] < bv) { bv = d[j]; bi = (unsigned)(j * 256 + tid); }
  for (int k = 0; k < 32; ++k) {
    float wmv = wave_min_bcast_f(bv);
    unsigned ci = (bv == wmv) ? bi : 0x7fffffffu;
    unsigned wmi = wave_min_bcast_u(ci);
    const int ksel = k & 1;
    if (lane == 0) { wv[ksel * 4 + wave] = wmv; wi[ksel * 4 + wave] = wmi; }
    __syncthreads();
    float gv = wv[ksel * 4]; unsigned gi = wi[ksel * 4];
#pragma unroll
    for (int w = 1; w < 4; ++w) {
      float ov = wv[ksel * 4 + w]; unsigned oi = wi[ksel * 4 + w];
      bool t = (ov < gv) || (ov == gv && oi < gi);
      gv = t ? ov : gv; gi = t ? oi : gi;
    }
    if (tid == 0) knn[(size_t)bid * 32 + k] = (int)gi;
    if ((gi & 255u) == (unsigned)tid) {  // winner rescans its candidates
      sel |= 1u << (gi >> 8);
      bv = 3.4e38f; bi = 0x7fffffffu;
#pragma unroll
      for (int j = 0; j < PT; ++j)
        if (!((sel >> j) & 1u) && d[j] < bv) { bv = d[j]; bi = (unsigned)(j * 256 + tid); }
    }
  }
}

// MFMA GEMM with chunked W-staging + BN stat partials.
template <int KD, int ND, bool GATHER, bool BNA, int NPTS, int S>
DEVI void gemm_body(char* smemraw, int bid, int tid, int gemmBlocks,
                    const short* A, const int* KNNp, const int* FPSp,
                    const short* __restrict__ W, const float* __restrict__ bnscale,
                    const float* __restrict__ bnshift, short* Hout,
                    float* __restrict__ partials) {
  constexpr int C = KD / 2;
  constexpr int NT = (ND > 128) ? 8 : ND / 16;
  constexpr int BR = (ND > 128) ? 64 : 128;
  constexpr int KC = (ND >= 256) ? 64 : KD;       // staging chunk k-width
  constexpr int LOG2KC = (KC == 64) ? 6 : 7;
  constexpr int NCH = KD / KC;
  constexpr int KTC = KC / 32;
  constexpr int LROW = KC + 8;                    // +16B pad -> 2-way alias (free)
  short* lb = (short*)smemraw;                    // [ND][LROW]
  float* lstats = (float*)(smemraw + ND * LROW * 2);
  const int wave = tid >> 6, lane = tid & 63;
  const int rowOff = (ND > 128) ? (wave >> 1) * 32 : wave * 32;
  const int colOff = (ND > 128) ? (wave & 1) * 128 : 0;
  const int mBase = bid * BR + rowOff;
  for (int i = tid; i < 2 * ND; i += 256) lstats[i] = 0.f;

  const short* aptr[2][2];
#pragma unroll
  for (int rg = 0; rg < 2; ++rg) {
    int m = mBase + rg * 16 + (lane & 15);
    if constexpr (GATHER) {
      int idx = KNNp[m];
      int bb = m / (S * 32);
      int s = (m - bb * (S * 32)) >> 5;
      int fidx = FPSp[bb * S + s];
      aptr[rg][0] = A + ((size_t)bb * NPTS + idx) * C;
      aptr[rg][1] = A + ((size_t)bb * NPTS + fidx) * C;
    } else {
      aptr[rg][0] = A + (size_t)m * KD;
      aptr[rg][1] = A + (size_t)m * KD + C;
    }
  }
  const int koLane = (lane >> 4) * 8;
  f32x4 acc[2][NT];
#pragma unroll
  for (int rg = 0; rg < 2; ++rg)
#pragma unroll
    for (int nt = 0; nt < NT; ++nt) acc[rg][nt] = (f32x4){0.f, 0.f, 0.f, 0.f};

#pragma unroll
  for (int ch = 0; ch < NCH; ++ch) {
    __syncthreads();
    constexpr int SIT = (ND * KC) / 2048;
#pragma unroll
    for (int i = 0; i < SIT; ++i) {
      int e = i * 2048 + tid * 8;
      int n = e >> LOG2KC, kk = e & (KC - 1);
      short8 v = *reinterpret_cast<const short8*>(W + (size_t)n * KD + ch * KC + kk);
      *reinterpret_cast<short8*>(&lb[n * LROW + kk]) = v;
    }
    __syncthreads();
#pragma unroll
    for (int ktc = 0; ktc < KTC; ++ktc) {
      const int kt = ch * KTC + ktc;
      const int half = (kt * 32 >= C) ? 1 : 0;
      const int ko = kt * 32 + koLane;
      const int koh = ko - half * C;
      short8 afrag[2];
#pragma unroll
      for (int rg = 0; rg < 2; ++rg) {
        short8 a = *reinterpret_cast<const short8*>(aptr[rg][half] + koh);
        if constexpr (BNA) {
          const float* scp = bnscale + ko;
          const float* shp = bnshift + ko;
#pragma unroll
          for (int j = 0; j < 8; ++j) {
            float v = h2f(a[j]);
            v = fmaxf(v * scp[j] + shp[j], 0.f);
            a[j] = f2h(v);
          }
        }
        afrag[rg] = a;
      }
#pragma unroll
      for (int nt = 0; nt < NT; ++nt) {
        short8 bfr = *reinterpret_cast<const short8*>(
            &lb[(colOff + nt * 16 + (lane & 15)) * LROW + ktc * 32 + koLane]);
        acc[0][nt] = mfma16(afrag[0], bfr, acc[0][nt]);
        acc[1][nt] = mfma16(afrag[1], bfr, acc[1][nt]);
      }
    }
  }
  __syncthreads();  // all A-reads done before in-place stores

#pragma unroll
  for (int nt = 0; nt < NT; ++nt) {
    float s0 = 0.f, s1 = 0.f;
#pragma unroll
    for (int rg = 0; rg < 2; ++rg)
#pragma unroll
      for (int i = 0; i < 4; ++i) {
        float v = acc[rg][nt][i];
        s0 += v; s1 += v * v;
      }
    s0 += __shfl_xor(s0, 16); s0 += __shfl_xor(s0, 32);
    s1 += __shfl_xor(s1, 16); s1 += __shfl_xor(s1, 32);
    if (lane < 16) {
      atomicAdd(&lstats[colOff + nt * 16 + lane], s0);
      atomicAdd(&lstats[ND + colOff + nt * 16 + lane], s1);
    }
  }
#pragma unroll
  for (int rg = 0; rg < 2; ++rg)
#pragma unroll
    for (int nt = 0; nt < NT; ++nt)
#pragma unroll
      for (int i = 0; i < 4; ++i) {
        int m2 = mBase + rg * 16 + (lane >> 4) * 4 + i;
        int n = colOff + nt * 16 + (lane & 15);
        Hout[(size_t)m2 * ND + n] = f2h(acc[rg][nt][i]);
      }
  __syncthreads();
  for (int i = tid; i < 2 * ND; i += 256)
    partials[(size_t)i * gemmBlocks + bid] = lstats[i];
}

// ---------- fused wrappers: fps segment blocks FIRST, companion after ----------

template <int FN, int FT>
__global__ __launch_bounds__(256, 1) void fps_stats_seg(
    int fpsBlocks, const float* fxyz, int* fout, float* fxyzc, int fnsel,
    int it0, int it1, float* dming, int* farg,
    const short* sh, float* sp, int sM, int snb) {
  extern __shared__ char smem[];
  if ((int)blockIdx.x < fpsBlocks)
    fps_seg_body<FN, FT>(smem, blockIdx.x, threadIdx.x, fxyz, fout, fxyzc, fnsel,
                         it0, it1, dming, farg);
  else
    stats64_body(blockIdx.x - fpsBlocks, snb, threadIdx.x, sh, sp, sM);
}

template <int FN, int FT>
__global__ __launch_bounds__(256, 1) void fps_r2_seg(
    int fpsBlocks, const float* fxyz, int* fout, float* fxyzc, int fnsel,
    int it0, int it1, float* dming, int* farg,
    const float* partials, const float* gamma, const float* beta,
    float* scale, float* shift, int NB, int C, float invM) {
  extern __shared__ char smem[];
  if ((int)blockIdx.x < fpsBlocks)
    fps_seg_body<FN, FT>(smem, blockIdx.x, threadIdx.x, fxyz, fout, fxyzc, fnsel,
                         it0, it1, dming, farg);
  else
    reduce2_body(blockIdx.x - fpsBlocks, threadIdx.x, partials, gamma, beta, scale,
                 shift, NB, C, invM);
}

template <int FN, int FT, int KD, int ND, bool BNA>
__global__ __launch_bounds__(256, 1) void fps_gemm_seg(
    int fpsBlocks, const float* fxyz, int* fout, float* fxyzc, int fnsel,
    int it0, int it1, float* dming, int* farg,
    const short* A, const short* W, const float* bnscale, const float* bnshift,
    short* Hout, float* partials) {
  extern __shared__ char smem[];
  if ((int)blockIdx.x < fpsBlocks)
    fps_seg_body<FN, FT>(smem, blockIdx.x, threadIdx.x, fxyz, fout, fxyzc, fnsel,
                         it0, it1, dming, farg);
  else
    gemm_body<KD, ND, false, BNA, 1, 1>(smem, blockIdx.x - fpsBlocks, threadIdx.x,
                                        gridDim.x - fpsBlocks, A, nullptr, nullptr,
                                        W, bnscale, bnshift, Hout, partials);
}

template <int FN, int FT>
__global__ __launch_bounds__(256, 1) void fps_apply_seg(
    int fpsBlocks, const float* fxyz, int* fout, float* fxyzc, int fnsel,
    int it0, int it1, float* dming, int* farg,
    const short* ah, short* af, const float* ascale, const float* ashift) {
  extern __shared__ char smem[];
  if ((int)blockIdx.x < fpsBlocks)
    fps_seg_body<FN, FT>(smem, blockIdx.x, threadIdx.x, fxyz, fout, fxyzc, fnsel,
                         it0, it1, dming, farg);
  else
    apply_body(blockIdx.x - fpsBlocks, threadIdx.x, ah, af, ascale, ashift);
}

// fps2 (full range) || gemm
template <int KD, int ND, bool BNA, int FN, int FT>
__global__ __launch_bounds__(256, 1) void gemm_fps_kernel(
    int fpsBlocks, const short* A, const short* W, const float* bnscale,
    const float* bnshift, short* Hout, float* partials,
    const float* fxyz, int* fout, float* fxyzc, int fnsel) {
  extern __shared__ char smem[];
  if ((int)blockIdx.x < fpsBlocks)
    fps_seg_body<FN, FT>(smem, blockIdx.x, threadIdx.x, fxyz, fout, fxyzc, fnsel,
                         0, fnsel, nullptr, nullptr);
  else
    gemm_body<KD, ND, false, BNA, 1, 1>(smem, blockIdx.x - fpsBlocks, threadIdx.x,
                                        gridDim.x - fpsBlocks, A, nullptr, nullptr,
                                        W, bnscale, bnshift, Hout, partials);
}

template <int KD, int ND, bool GATHER, bool BNA, int NPTS, int S>
__global__ __launch_bounds__(256, 2) void gemm_kernel(
    const short* A, const int* KNNp, const int* FPSp, const short* W,
    const float* bnscale, const float* bnshift, short* Hout, float* partials) {
  extern __shared__ char smem[];
  gemm_body<KD, ND, GATHER, BNA, NPTS, S>(smem, blockIdx.x, threadIdx.x, gridDim.x,
                                          A, KNNp, FPSp, W, bnscale, bnshift, Hout,
                                          partials);
}

// standalone knn (4 blocks/CU for latency hiding)
template <int NPTS, int S>
__global__ __launch_bounds__(256, 4) void knn_kernel2(
    const float* pts, const int* fpsidx, int* knn) {
  __shared__ char smem[64];
  knn_body<NPTS, S>(smem, blockIdx.x, threadIdx.x, pts, fpsidx, knn);
}

// knn blocks first, then maxpool-f1 blocks (2 rows per 256-thr block)
template <int NPTS, int S>
__global__ __launch_bounds__(256, 4) void maxpool_knn_kernel(
    int knnBlocks, const float* pts, const int* fpsidx, int* knn,
    const short* h, const float* scale, const float* shift, short* f1) {
  __shared__ char smem[64];
  if ((int)blockIdx.x < knnBlocks) {
    knn_body<NPTS, S>(smem, blockIdx.x, threadIdx.x, pts, fpsidx, knn);
  } else {
    const int bs = (blockIdx.x - knnBlocks) * 2 + (threadIdx.x >> 7);
    const int c = threadIdx.x & 127;
    const float sc = scale[c], sh = shift[c];
    float m = 0.f;  // relu outputs >= 0
    for (int k = 0; k < 32; ++k) {
      float v = h2f(h[((size_t)bs * 32 + k) * 128 + c]);
      m = fmaxf(m, fmaxf(v * sc + sh, 0.f));
    }
    f1[(size_t)bs * 128 + c] = f2h(m);
  }
}

// ---------- final: max over K with BN+ReLU, transposed fp32 out [B][C][S] ----------
__global__ __launch_bounds__(256) void maxpool_out_kernel(
    const short* __restrict__ h, const float* __restrict__ scale,
    const float* __restrict__ shift, float* __restrict__ out) {
  const int bs = blockIdx.x, c = threadIdx.x;
  const int b = bs >> 8, s = bs & 255;
  const float sc = scale[c], sh = shift[c];
  float m = 0.f;
  for (int k = 0; k < 32; ++k) {
    float v = h2f(h[((size_t)bs * 32 + k) * 256 + c]);
    m = fmaxf(m, fmaxf(v * sc + sh, 0.f));
  }
  out[((size_t)b << 16) + ((size_t)c << 8) + s] = m;
}

// ---------- launch ----------
extern "C" void kernel_launch(void* const* d_in, const int* in_sizes, int n_in,
                              void* d_out, int out_size, void* d_ws, size_t ws_size,
                              hipStream_t stream) {
  (void)in_sizes; (void)n_in; (void)out_size; (void)ws_size;
  const float* x    = (const float*)d_in[0];
  const float* w1   = (const float*)d_in[1];
  const float* g1   = (const float*)d_in[2];
  const float* b1   = (const float*)d_in[3];
  const float* w2   = (const float*)d_in[4];
  const float* g2   = (const float*)d_in[5];
  const float* b2   = (const float*)d_in[6];
  const float* s1w1 = (const float*)d_in[7];
  const float* s1g1 = (const float*)d_in[8];
  const float* s1b1 = (const float*)d_in[9];
  const float* s1w2 = (const float*)d_in[10];
  const float* s1g2 = (const float*)d_in[11];
  const float* s1b2 = (const float*)d_in[12];
  const float* s2w1 = (const float*)d_in[13];
  const float* s2g1 = (const float*)d_in[14];
  const float* s2b1 = (const float*)d_in[15];
  const float* s2w2 = (const float*)d_in[16];
  const float* s2g2 = (const float*)d_in[17];
  const float* s2b2 = (const float*)d_in[18];
  float* out = (float*)d_out;

  char* ws = (char*)d_ws;
  size_t off = 0;
  auto alloc = [&](size_t bytes) -> char* {
    size_t p = (off + 255) & ~(size_t)255;
    off = p + bytes;
    return ws + p;
  };

  float* xyz      = (float*)alloc(32ull * 4096 * 3 * 4);
  short* h0       = (short*)alloc(32ull * 4096 * 64 * 2);
  short* hb       = (short*)alloc(32ull * 4096 * 64 * 2);
  short* fb       = (short*)alloc(32ull * 4096 * 64 * 2);
  int*   fps1     = (int*)alloc(32ull * 512 * 4);
  float* xyzc1    = (float*)alloc(32ull * 512 * 3 * 4);
  int*   knn1     = (int*)alloc(32ull * 512 * 32 * 4);
  short* f1       = (short*)alloc(32ull * 512 * 128 * 2);
  int*   fps2     = (int*)alloc(32ull * 256 * 4);
  int*   knn2     = (int*)alloc(32ull * 256 * 32 * 4);
  float* dming    = (float*)alloc(32ull * 4096 * 4);     // fps1 segment state
  int*   farg     = (int*)alloc(32 * 4);
  short* hbuf     = (short*)alloc(134217728ull);          // shared SG1/SG2 h buffer
  float* partials = (float*)alloc(2ull * 256 * 4096 * 4); // 8 MB
  float* scA  = (float*)alloc(64 * 4);  float* shA  = (float*)alloc(64 * 4);
  float* scBc = (float*)alloc(64 * 4);  float* shBc = (float*)alloc(64 * 4);
  float* sc1a = (float*)alloc(128 * 4); float* sh1a = (float*)alloc(128 * 4);
  float* sc1b = (float*)alloc(128 * 4); float* sh1b = (float*)alloc(128 * 4);
  float* sc2a = (float*)alloc(256 * 4); float* sh2a = (float*)alloc(256 * 4);
  float* sc2b = (float*)alloc(256 * 4); float* sh2b = (float*)alloc(256 * 4);
  short* w2b   = (short*)alloc(4096 * 2);
  short* s1w2b = (short*)alloc(16384 * 2);
  short* s2w2b = (short*)alloc(65536 * 2);
  short* W1pp  = (short*)alloc(16384 * 2);
  short* W2pp  = (short*)alloc(65536 * 2);

  prep_kernel<<<656, 256, 0, stream>>>(w2, s1w2, s2w2, s1w1, s2w1, w2b, s1w2b, s2w2b, W1pp, W2pp);
  stageA_kernel<<<512, 256, 0, stream>>>(x, w1, xyz, h0);

  // fps1 segmented across 5 launches; MLP chain hides as companion blocks
  fps_stats_seg<4096, 256><<<288, 256, 49216, stream>>>(
      32, xyz, fps1, xyzc1, 512, 0, 103, dming, farg, h0, partials, 131072, 256);
  fps_r2_seg<4096, 256><<<96, 256, 49216, stream>>>(
      32, xyz, fps1, xyzc1, 512, 103, 205, dming, farg,
      partials, g1, b1, scA, shA, 256, 64, 1.f / 131072.f);
  fps_gemm_seg<4096, 256, 64, 64, true><<<1056, 256, 49216, stream>>>(
      32, xyz, fps1, xyzc1, 512, 205, 308, dming, farg,
      h0, w2b, scA, shA, hb, partials);
  fps_r2_seg<4096, 256><<<96, 256, 49216, stream>>>(
      32, xyz, fps1, xyzc1, 512, 308, 410, dming, farg,
      partials, g2, b2, scBc, shBc, 1024, 64, 1.f / 131072.f);
  fps_apply_seg<4096, 256><<<4128, 256, 49216, stream>>>(
      32, xyz, fps1, xyzc1, 512, 410, 512, dming, farg, hb, fb, scBc, shBc);

  knn_kernel2<4096, 512><<<16384, 256, 0, stream>>>(xyz, fps1, knn1);

  gemm_kernel<128, 128, true, false, 4096, 512><<<4096, 256, 35840, stream>>>(
      fb, knn1, fps1, W1pp, nullptr, nullptr, hbuf, partials);
  reduce2_kernel<<<128, 256, 0, stream>>>(partials, s1g1, s1b1, sc1a, sh1a, 4096, 128, 1.f / 524288.f);

  // fps2 (32 blocks) || SG1 gemm2 in-place BNA (4096 blocks)
  gemm_fps_kernel<128, 128, true, 512, 256><<<4128, 256, 35840, stream>>>(
      32, hbuf, s1w2b, sc1a, sh1a, hbuf, partials, xyzc1, fps2, nullptr, 256);
  reduce2_kernel<<<128, 256, 0, stream>>>(partials, s1g2, s1b2, sc1b, sh1b, 4096, 128, 1.f / 524288.f);

  // knn2 (8192 blocks) || maxpool_f1 (8192 blocks, 2 rows each)
  maxpool_knn_kernel<512, 256><<<16384, 256, 0, stream>>>(
      8192, xyzc1, fps2, knn2, hbuf, sc1b, sh1b, f1);

  gemm_kernel<256, 256, true, false, 512, 256><<<4096, 256, 38912, stream>>>(
      f1, knn2, fps2, W2pp, nullptr, nullptr, hbuf, partials);
  reduce2_kernel<<<256, 256, 0, stream>>>(partials, s2g1, s2b1, sc2a, sh2a, 4096, 256, 1.f / 262144.f);
  gemm_kernel<256, 256, false, true, 1, 1><<<4096, 256, 38912, stream>>>(
      hbuf, nullptr, nullptr, s2w2b, sc2a, sh2a, hbuf, partials);
  reduce2_kernel<<<256, 256, 0, stream>>>(partials, s2g2, s2b2, sc2b, sh2b, 4096, 256, 1.f / 262144.f);
  maxpool_out_kernel<<<8192, 256, 0, stream>>>(hbuf, sc2b, sh2b, out);
}